// Round 8
// baseline (644.361 us; speedup 1.0000x reference)
//
#include <hip/hip_runtime.h>
#include <math.h>

#define NNODES 50000
#define NEDGES 1600000
#define DIM    128
#define NHID   (NNODES * DIM)      // 6,400,000
#define TPB    256
#define NTILES ((NNODES + 63) / 64)   // 782, 64 rows per block-tile

// binned CSR build
#define NBINS  196                 // ceil(50000/256)
#define BINSZ  256                 // nodes per bin (dst>>8)
#define EPT    16                  // edges per thread in binning passes
#define CHUNK  (TPB * EPT)         // 4096 edges per block
#define NCHUNKS ((NEDGES + CHUNK - 1) / CHUNK)   // 391
#define BINCAP 10240               // staged edges per bin (mean 8192, sigma 90)

#define WMAT   (128 * 136)         // one padded W^T matrix (bf16 elems)
#define NWMAT  14                  // 2 paths x (3xW1 + 3xW2 + Wo)

typedef unsigned short bf16_t;
typedef __attribute__((ext_vector_type(8))) short short8;   // 8 bf16, 4 VGPRs
typedef __attribute__((ext_vector_type(4))) float f32x4;    // MFMA acc

__device__ __forceinline__ float bf_lo(unsigned u) { return __uint_as_float(u << 16); }
__device__ __forceinline__ float bf_hi(unsigned u) { return __uint_as_float(u & 0xFFFF0000u); }
__device__ __forceinline__ bf16_t f2bf(float f) {   // RNE
    unsigned u = __float_as_uint(f);
    u += 0x7FFFu + ((u >> 16) & 1u);
    return (bf16_t)(u >> 16);
}
__device__ __forceinline__ unsigned pack2bf(float a, float b) {
    return (unsigned)f2bf(a) | ((unsigned)f2bf(b) << 16);
}

union S8U { short8 v; uint4 u4; unsigned us[4]; };

// ===========================================================================
// CSR build, dense-write pipeline (round-2 proven):
//   bin_hist -> bin_scan -> bin_scatter (packed dl<<16|src) -> build_csr
//   (per-bin LDS counting sort -> per-node off[] + sorted src bucket).
// ===========================================================================
__global__ __launch_bounds__(TPB) void bin_hist_kernel(
    const int* __restrict__ dst, int* __restrict__ gcnt)
{
    __shared__ int lcnt[NBINS];
    const int tid = threadIdx.x;
    for (int i = tid; i < NBINS; i += TPB) lcnt[i] = 0;
    __syncthreads();
    const int base = blockIdx.x * CHUNK;
    #pragma unroll
    for (int k = 0; k < EPT; ++k) {
        int e = base + k * TPB + tid;
        if (e < NEDGES) atomicAdd(&lcnt[dst[e] >> 8], 1);
    }
    __syncthreads();
    for (int i = tid; i < NBINS; i += TPB) {
        int c = lcnt[i];
        if (c) atomicAdd(&gcnt[i], c);
    }
}

__global__ __launch_bounds__(64) void bin_scan_kernel(
    const int* __restrict__ gcnt, int* __restrict__ start, int* __restrict__ bcur,
    int* __restrict__ off)
{
    const int lane = threadIdx.x;   // 64 lanes, each owns 4 bins
    int c[4];
    int s = 0;
    #pragma unroll
    for (int k = 0; k < 4; ++k) {
        int b = 4 * lane + k;
        c[k] = (b < NBINS) ? gcnt[b] : 0;
        s += c[k];
    }
    int incl = s;
    #pragma unroll
    for (int d = 1; d < 64; d <<= 1) {
        int t = __shfl_up(incl, d);
        if (lane >= d) incl += t;
    }
    int excl = incl - s;
    #pragma unroll
    for (int k = 0; k < 4; ++k) {
        int b = 4 * lane + k;
        if (b < NBINS) { start[b] = excl; bcur[b] = excl; }
        excl += c[k];
    }
    if (lane == 63) { start[NBINS] = excl; off[NNODES] = excl; }   // == NEDGES
}

__global__ __launch_bounds__(TPB) void bin_scatter_kernel(
    const int* __restrict__ src, const int* __restrict__ dst,
    int* __restrict__ bcur, unsigned* __restrict__ bucket)
{
    __shared__ int lcnt[NBINS];    // phase A: counts
    __shared__ int lcur[NBINS];    // phase C: absolute cursors
    const int tid = threadIdx.x;
    for (int i = tid; i < NBINS; i += TPB) lcnt[i] = 0;
    __syncthreads();

    unsigned pk[EPT];
    int bn[EPT];
    const int base = blockIdx.x * CHUNK;
    #pragma unroll
    for (int k = 0; k < EPT; ++k) {
        int e = base + k * TPB + tid;
        int b = -1; unsigned p = 0;
        if (e < NEDGES) {
            int d = dst[e];
            int s = src[e];
            b = d >> 8;
            p = ((unsigned)(d & 255) << 16) | (unsigned)s;
            atomicAdd(&lcnt[b], 1);
        }
        pk[k] = p; bn[k] = b;
    }
    __syncthreads();
    for (int i = tid; i < NBINS; i += TPB) {
        int c = lcnt[i];
        lcur[i] = (c > 0) ? atomicAdd(&bcur[i], c) : 0;
    }
    __syncthreads();
    #pragma unroll
    for (int k = 0; k < EPT; ++k) {
        if (bn[k] >= 0) {
            int p = atomicAdd(&lcur[bn[k]], 1);
            bucket[p] = pk[k];
        }
    }
}

__global__ __launch_bounds__(TPB) void build_csr_kernel(
    const int* __restrict__ start, unsigned* __restrict__ bucket,
    int* __restrict__ off)
{
    __shared__ unsigned se[BINCAP];   // staged bin edges, 40 KB
    __shared__ int lcnt[BINSZ];
    __shared__ int lofs[BINSZ];
    __shared__ int wsum[4];
    const int tid = threadIdx.x;
    const int b = blockIdx.x;
    const int j0 = start[b], j1 = start[b + 1];
    const int n = j1 - j0;            // <= BINCAP by construction

    lcnt[tid] = 0;
    for (int i = tid; i < n; i += TPB) se[i] = bucket[j0 + i];
    __syncthreads();
    for (int i = tid; i < n; i += TPB) atomicAdd(&lcnt[se[i] >> 16], 1);
    __syncthreads();

    // exclusive scan of lcnt[256] across 4 waves
    const int lane = tid & 63, wid = tid >> 6;
    int v = lcnt[tid];
    int s = v;
    #pragma unroll
    for (int d = 1; d < 64; d <<= 1) {
        int t = __shfl_up(s, d);
        if (lane >= d) s += t;
    }
    if (lane == 63) wsum[wid] = s;
    __syncthreads();
    if (tid == 0) {
        int a = 0;
        #pragma unroll
        for (int k = 0; k < 4; ++k) { int t = wsum[k]; wsum[k] = a; a += t; }
    }
    __syncthreads();
    int excl = wsum[wid] + s - v;
    lofs[tid] = excl;
    int node = b * BINSZ + tid;
    if (node < NNODES) off[node] = j0 + excl;
    __syncthreads();

    // in-place counting-sort scatter (safe: all edges staged in LDS)
    for (int i = tid; i < n; i += TPB) {
        unsigned e = se[i];
        int pos = atomicAdd(&lofs[e >> 16], 1);
        bucket[j0 + pos] = e & 0xFFFFu;   // src node id
    }
}

// ---------------------------------------------------------------------------
// One-time weight preconversion: all 14 matrices -> bf16 W^T in the exact
// padded [128][136] layout the LDS staging uses. Matrix b = p*7 + s,
// s: 0..2 = W1 layer, 3..5 = W2 layer, 6 = Wout.
// ---------------------------------------------------------------------------
__global__ __launch_bounds__(TPB) void convert_weights_kernel(
    const float* __restrict__ W1_0, const float* __restrict__ W2_0,
    const float* __restrict__ Wo_0,
    const float* __restrict__ W1_1, const float* __restrict__ W2_1,
    const float* __restrict__ Wo_1,
    bf16_t* __restrict__ wpre)
{
    const int b = blockIdx.x;
    const int p = b / 7, s = b % 7;
    const float* W;
    if (s < 3)      W = (p ? W1_1 : W1_0) + (size_t)s * DIM * DIM;
    else if (s < 6) W = (p ? W2_1 : W2_0) + (size_t)(s - 3) * DIM * DIM;
    else            W = p ? Wo_1 : Wo_0;
    bf16_t* dst = wpre + (size_t)b * WMAT;

    for (int idx = threadIdx.x; idx < 128 * 16; idx += TPB) {
        int n = idx & 127, koct = idx >> 7;
        float f[8];
        #pragma unroll
        for (int j = 0; j < 8; ++j) f[j] = W[(8 * koct + j) * 128 + n];
        uint4 u;
        u.x = pack2bf(f[0], f[1]); u.y = pack2bf(f[2], f[3]);
        u.z = pack2bf(f[4], f[5]); u.w = pack2bf(f[6], f[7]);
        *(uint4*)&dst[n * 136 + 8 * koct] = u;
    }
}

// ---------------------------------------------------------------------------
// Gather aggregation, wave per node, 16/8/1-deep ILP (round-7 proven).
// ---------------------------------------------------------------------------
__global__ __launch_bounds__(TPB) void gather_agg_f32_kernel(
    const float* __restrict__ h, const int* __restrict__ off,
    const unsigned* __restrict__ bucket, float* __restrict__ acat)
{
    int node = blockIdx.x * (TPB / 64) + (threadIdx.x >> 6);
    int lane = threadIdx.x & 63;
    if (node >= NNODES) return;
    int j0 = off[node], j1 = off[node + 1];
    const float* base = h + 2 * lane;
    float ax = 0.0f, ay = 0.0f;
    int j = j0;
    for (; j + 16 <= j1; j += 16) {
        unsigned s[16];
        #pragma unroll
        for (int k = 0; k < 16; ++k) s[k] = bucket[j + k];
        float2 v[16];
        #pragma unroll
        for (int k = 0; k < 16; ++k) v[k] = *(const float2*)(base + (size_t)s[k] * DIM);
        #pragma unroll
        for (int k = 0; k < 16; ++k) { ax += v[k].x; ay += v[k].y; }
    }
    for (; j + 8 <= j1; j += 8) {
        unsigned s[8];
        #pragma unroll
        for (int k = 0; k < 8; ++k) s[k] = bucket[j + k];
        float2 v[8];
        #pragma unroll
        for (int k = 0; k < 8; ++k) v[k] = *(const float2*)(base + (size_t)s[k] * DIM);
        #pragma unroll
        for (int k = 0; k < 8; ++k) { ax += v[k].x; ay += v[k].y; }
    }
    for (; j < j1; ++j) {
        float2 v0 = *(const float2*)(base + (size_t)bucket[j] * DIM);
        ax += v0.x; ay += v0.y;
    }
    *(float2*)(acat + (size_t)node * 256 + 2 * lane) = make_float2(ax, ay);
}

__global__ __launch_bounds__(TPB) void gather_cat_kernel(
    const bf16_t* __restrict__ hc, const int* __restrict__ off,
    const unsigned* __restrict__ bucket, float* __restrict__ acat)
{
    int node = blockIdx.x * (TPB / 64) + (threadIdx.x >> 6);
    int lane = threadIdx.x & 63;
    if (node >= NNODES) return;
    int j0 = off[node], j1 = off[node + 1];
    const uint2* base = (const uint2*)hc + lane;   // 64 uint2 per 512B row
    float a0 = 0.f, a1 = 0.f, a2 = 0.f, a3 = 0.f;
    int j = j0;
    for (; j + 16 <= j1; j += 16) {
        unsigned s[16];
        #pragma unroll
        for (int k = 0; k < 16; ++k) s[k] = bucket[j + k];
        uint2 u[16];
        #pragma unroll
        for (int k = 0; k < 16; ++k) u[k] = base[(size_t)s[k] * 64];
        #pragma unroll
        for (int k = 0; k < 16; ++k) {
            a0 += bf_lo(u[k].x); a1 += bf_hi(u[k].x);
            a2 += bf_lo(u[k].y); a3 += bf_hi(u[k].y);
        }
    }
    for (; j + 8 <= j1; j += 8) {
        unsigned s[8];
        #pragma unroll
        for (int k = 0; k < 8; ++k) s[k] = bucket[j + k];
        uint2 u[8];
        #pragma unroll
        for (int k = 0; k < 8; ++k) u[k] = base[(size_t)s[k] * 64];
        #pragma unroll
        for (int k = 0; k < 8; ++k) {
            a0 += bf_lo(u[k].x); a1 += bf_hi(u[k].x);
            a2 += bf_lo(u[k].y); a3 += bf_hi(u[k].y);
        }
    }
    for (; j < j1; ++j) {
        uint2 u = base[(size_t)bucket[j] * 64];
        a0 += bf_lo(u.x); a1 += bf_hi(u.x);
        a2 += bf_lo(u.y); a3 += bf_hi(u.y);
    }
    // lane<32: mean cols 4l..4l+3 -> acat[4l..]; lane>=32: std cols -> 128+...
    *(float4*)(acat + (size_t)node * 256 + 4 * lane) = make_float4(a0, a1, a2, a3);
}

// ---------------------------------------------------------------------------
// FUSED GIN layer v3 (round-7 structure + preconverted weights):
//   out_half = sigmoid(z@W1+b1)@W2+b2, z = (1+eps)*hin_half + agg_half.
//   ONE W LDS buffer (W1 then W2) + bf16 y1 = 52.2 KB -> 3 blocks/CU;
//   W staging = pure uint4 memcpy from wpre (fallback: in-kernel convert).
//   __launch_bounds__(TPB,4) caps VGPR at 128 -> 12 waves/CU.
// ---------------------------------------------------------------------------
template <class HinT, int INSTRIDE>
__global__ __launch_bounds__(TPB, 4) void fused_layer_kernel(
    const HinT* __restrict__ hin, const float* __restrict__ acat, int aggByPath,
    const float* __restrict__ eps0, const float* __restrict__ eps1, int eps_idx,
    const float* __restrict__ W1_0, const float* __restrict__ b1_0,
    const float* __restrict__ W2_0, const float* __restrict__ b2_0,
    const float* __restrict__ W1_1, const float* __restrict__ b1_1,
    const float* __restrict__ W2_1, const float* __restrict__ b2_1,
    const bf16_t* __restrict__ wpre,
    bf16_t* __restrict__ out)
{
    __shared__ short sWt[128 * 136];   // 34.8 KB: W1^T, then W2^T
    __shared__ short y1b[64 * 136];    // 17.4 KB: bf16 y1

    const int p = (blockIdx.x >= NTILES) ? 1 : 0;
    const int t = blockIdx.x - p * NTILES;
    const int l = eps_idx;
    const float* W1 = p ? W1_1 : W1_0;
    const float* b1 = p ? b1_1 : b1_0;
    const float* W2 = p ? W2_1 : W2_0;
    const float* b2 = p ? b2_1 : b2_0;
    const float* epsp = p ? eps1 : eps0;
    const HinT* hbase = (INSTRIDE == 256) ? (hin + p * 128) : hin;
    const float* abase = acat + (aggByPath ? p * 128 : 0);
    bf16_t* ob = out + p * 128;

    const int tid = threadIdx.x;
    // ---- stage W1^T ----
    if (wpre) {
        const uint4* s = (const uint4*)(wpre + (size_t)(p * 7 + l) * WMAT);
        uint4* d = (uint4*)sWt;
        #pragma unroll
        for (int i = 0; i < 9; ++i) {
            int idx = i * 256 + tid;
            if (idx < WMAT / 8) d[idx] = s[idx];
        }
    } else {
        #pragma unroll
        for (int it = 0; it < 8; ++it) {
            int idx = it * 256 + tid;
            int n = idx & 127, koct = idx >> 7;
            float f1[8];
            #pragma unroll
            for (int j = 0; j < 8; ++j) f1[j] = W1[(8 * koct + j) * 128 + n];
            uint4 u1;
            u1.x = pack2bf(f1[0], f1[1]); u1.y = pack2bf(f1[2], f1[3]);
            u1.z = pack2bf(f1[4], f1[5]); u1.w = pack2bf(f1[6], f1[7]);
            *(uint4*)&sWt[n * 136 + 8 * koct] = u1;
        }
    }
    __syncthreads();

    const int lane = tid & 63, w = tid >> 6;
    const int m = lane & 15, quad = lane >> 4;

    const float scale = 1.0f + epsp[eps_idx];
    float b1v[8], b2v[8];
    #pragma unroll
    for (int c = 0; c < 8; ++c) { b1v[c] = b1[16 * c + m]; b2v[c] = b2[16 * c + m]; }

    const int arow = min(t * 64 + 16 * w + m, NNODES - 1);

    // ---- A-fragments: z = scale*hin + agg, hi/lo split ----
    short8 afh[4], afl[4];
    #pragma unroll
    for (int k0 = 0; k0 < 4; ++k0) {
        const int kb = 32 * k0 + 8 * quad;
        float zf[8];
        if constexpr (sizeof(HinT) == 4) {
            const float* hp = (const float*)hbase + (size_t)arow * INSTRIDE + kb;
            float4 h0 = *(const float4*)hp;
            float4 h1 = *(const float4*)(hp + 4);
            zf[0] = h0.x; zf[1] = h0.y; zf[2] = h0.z; zf[3] = h0.w;
            zf[4] = h1.x; zf[5] = h1.y; zf[6] = h1.z; zf[7] = h1.w;
        } else {
            uint4 hu = *(const uint4*)((const bf16_t*)hbase + (size_t)arow * INSTRIDE + kb);
            zf[0] = bf_lo(hu.x); zf[1] = bf_hi(hu.x);
            zf[2] = bf_lo(hu.y); zf[3] = bf_hi(hu.y);
            zf[4] = bf_lo(hu.z); zf[5] = bf_hi(hu.z);
            zf[6] = bf_lo(hu.w); zf[7] = bf_hi(hu.w);
        }
        const float* ap = abase + (size_t)arow * 256 + kb;
        float4 a0 = *(const float4*)ap;
        float4 a1 = *(const float4*)(ap + 4);
        zf[0] = fmaf(scale, zf[0], a0.x); zf[1] = fmaf(scale, zf[1], a0.y);
        zf[2] = fmaf(scale, zf[2], a0.z); zf[3] = fmaf(scale, zf[3], a0.w);
        zf[4] = fmaf(scale, zf[4], a1.x); zf[5] = fmaf(scale, zf[5], a1.y);
        zf[6] = fmaf(scale, zf[6], a1.z); zf[7] = fmaf(scale, zf[7], a1.w);
        S8U hi;
        hi.us[0] = pack2bf(zf[0], zf[1]); hi.us[1] = pack2bf(zf[2], zf[3]);
        hi.us[2] = pack2bf(zf[4], zf[5]); hi.us[3] = pack2bf(zf[6], zf[7]);
        afh[k0] = hi.v;
        S8U lo;
        float lw[8];
        lw[0] = zf[0] - bf_lo(hi.us[0]); lw[1] = zf[1] - bf_hi(hi.us[0]);
        lw[2] = zf[2] - bf_lo(hi.us[1]); lw[3] = zf[3] - bf_hi(hi.us[1]);
        lw[4] = zf[4] - bf_lo(hi.us[2]); lw[5] = zf[5] - bf_hi(hi.us[2]);
        lw[6] = zf[6] - bf_lo(hi.us[3]); lw[7] = zf[7] - bf_hi(hi.us[3]);
        lo.us[0] = pack2bf(lw[0], lw[1]); lo.us[1] = pack2bf(lw[2], lw[3]);
        lo.us[2] = pack2bf(lw[4], lw[5]); lo.us[3] = pack2bf(lw[6], lw[7]);
        afl[k0] = lo.v;
    }

    // ---- MFMA1: B-frags from LDS (read once per (k0,c), used twice) ----
    f32x4 acc[8];
    #pragma unroll
    for (int c = 0; c < 8; ++c) acc[c] = (f32x4){0.f, 0.f, 0.f, 0.f};
    #pragma unroll
    for (int k0 = 0; k0 < 4; ++k0) {
        const int kb = 32 * k0 + 8 * quad;
        #pragma unroll
        for (int c = 0; c < 8; ++c) {
            short8 bfr = *(const short8*)&sWt[(16 * c + m) * 136 + kb];
            acc[c] = __builtin_amdgcn_mfma_f32_16x16x32_bf16(afl[k0], bfr, acc[c], 0, 0, 0);
            acc[c] = __builtin_amdgcn_mfma_f32_16x16x32_bf16(afh[k0], bfr, acc[c], 0, 0, 0);
        }
    }

    // ---- sigmoid + stage y1 as bf16 ----
    const int rloc0 = 16 * w + 4 * quad;   // local row in [0,64)
    #pragma unroll
    for (int r = 0; r < 4; ++r) {
        #pragma unroll
        for (int c = 0; c < 8; ++c) {
            float y = acc[c][r] + b1v[c];
            y = 1.0f / (1.0f + expf(-y));
            y1b[(rloc0 + r) * 136 + 16 * c + m] = (short)f2bf(y);
        }
    }
    __syncthreads();   // MFMA1 sWt reads + y1 writes complete

    // ---- stage W2^T into the same buffer ----
    if (wpre) {
        const uint4* s = (const uint4*)(wpre + (size_t)(p * 7 + 3 + l) * WMAT);
        uint4* d = (uint4*)sWt;
        #pragma unroll
        for (int i = 0; i < 9; ++i) {
            int idx = i * 256 + tid;
            if (idx < WMAT / 8) d[idx] = s[idx];
        }
    } else {
        #pragma unroll
        for (int it = 0; it < 8; ++it) {
            int idx = it * 256 + tid;
            int n = idx & 127, koct = idx >> 7;
            float f2[8];
            #pragma unroll
            for (int j = 0; j < 8; ++j) f2[j] = W2[(8 * koct + j) * 128 + n];
            uint4 u2;
            u2.x = pack2bf(f2[0], f2[1]); u2.y = pack2bf(f2[2], f2[3]);
            u2.z = pack2bf(f2[4], f2[5]); u2.w = pack2bf(f2[6], f2[7]);
            *(uint4*)&sWt[n * 136 + 8 * koct] = u2;
        }
    }
    __syncthreads();

    // ---- MFMA2: A from y1b (bf16 direct), B from sWt ----
    f32x4 acc2[8];
    #pragma unroll
    for (int c = 0; c < 8; ++c) acc2[c] = (f32x4){0.f, 0.f, 0.f, 0.f};
    #pragma unroll
    for (int k0 = 0; k0 < 4; ++k0) {
        const int kb = 32 * k0 + 8 * quad;
        short8 a2 = *(const short8*)&y1b[(16 * w + m) * 136 + kb];
        #pragma unroll
        for (int c = 0; c < 8; ++c) {
            short8 b2f = *(const short8*)&sWt[(16 * c + m) * 136 + kb];
            acc2[c] = __builtin_amdgcn_mfma_f32_16x16x32_bf16(a2, b2f, acc2[c], 0, 0, 0);
        }
    }

    // ---- epilogue: h_out = acc2 + b2 (bf16, stride 256) ----
    const int row0 = t * 64 + 16 * w + 4 * quad;
    #pragma unroll
    for (int r = 0; r < 4; ++r) {
        const int grow = row0 + r;
        if (grow < NNODES) {
            bf16_t* op = ob + (size_t)grow * 256 + m;
            #pragma unroll
            for (int c = 0; c < 8; ++c) op[16 * c] = f2bf(acc2[c][r] + b2v[c]);
        }
    }
}

// ---------------------------------------------------------------------------
// Final projection + layernorm, both paths in one grid:
//   out(p) = layernorm(h_cat(p) @ Wout + bout) * gamma + beta  (fp32)
// ---------------------------------------------------------------------------
__global__ __launch_bounds__(TPB) void final_proj_kernel(
    const bf16_t* __restrict__ hc,
    const float* __restrict__ Wo0, const float* __restrict__ bo0,
    const float* __restrict__ Wo1, const float* __restrict__ bo1,
    const float* __restrict__ gamma, const float* __restrict__ beta,
    const bf16_t* __restrict__ wpre,
    float* __restrict__ M, float* __restrict__ V)
{
    __shared__ short sWt[128 * 136];   // bf16 W^T

    const int p = (blockIdx.x >= NTILES) ? 1 : 0;
    const int t = blockIdx.x - p * NTILES;
    const float* W = p ? Wo1 : Wo0;
    const float* bias = p ? bo1 : bo0;
    const bf16_t* hbase = hc + p * 128;
    float* out = p ? V : M;

    const int tid = threadIdx.x;
    if (wpre) {
        const uint4* s = (const uint4*)(wpre + (size_t)(p * 7 + 6) * WMAT);
        uint4* d = (uint4*)sWt;
        #pragma unroll
        for (int i = 0; i < 9; ++i) {
            int idx = i * 256 + tid;
            if (idx < WMAT / 8) d[idx] = s[idx];
        }
    } else {
        #pragma unroll
        for (int it = 0; it < 8; ++it) {
            int idx = it * 256 + tid;
            int n = idx & 127, koct = idx >> 7;
            float f[8];
            #pragma unroll
            for (int j = 0; j < 8; ++j) f[j] = W[(8 * koct + j) * 128 + n];
            uint4 u;
            u.x = pack2bf(f[0], f[1]); u.y = pack2bf(f[2], f[3]);
            u.z = pack2bf(f[4], f[5]); u.w = pack2bf(f[6], f[7]);
            *(uint4*)&sWt[n * 136 + 8 * koct] = u;
        }
    }
    __syncthreads();

    const int lane = tid & 63, w = tid >> 6;
    const int m = lane & 15, quad = lane >> 4;

    short8 bf[32];
    #pragma unroll
    for (int c = 0; c < 8; ++c)
        #pragma unroll
        for (int k0 = 0; k0 < 4; ++k0)
            bf[c * 4 + k0] = *(const short8*)&sWt[(16 * c + m) * 136 + 32 * k0 + 8 * quad];

    float bias_v[8], g_v[8], bt_v[8];
    #pragma unroll
    for (int c = 0; c < 8; ++c) {
        bias_v[c] = bias[16 * c + m];
        g_v[c] = gamma[16 * c + m];
        bt_v[c] = beta[16 * c + m];
    }

    const int arow = min(t * 64 + 16 * w + m, NNODES - 1);
    short8 af[4];
    #pragma unroll
    for (int k0 = 0; k0 < 4; ++k0)
        af[k0] = *(const short8*)(hbase + (size_t)arow * 256 + 32 * k0 + 8 * quad);

    f32x4 acc[8];
    #pragma unroll
    for (int c = 0; c < 8; ++c) acc[c] = (f32x4){0.f, 0.f, 0.f, 0.f};
    #pragma unroll
    for (int k0 = 0; k0 < 4; ++k0)
        #pragma unroll
        for (int c = 0; c < 8; ++c)
            acc[c] = __builtin_amdgcn_mfma_f32_16x16x32_bf16(
                af[k0], bf[c * 4 + k0], acc[c], 0, 0, 0);

    const int row0 = t * 64 + 16 * w + 4 * quad;
    #pragma unroll
    for (int r = 0; r < 4; ++r) {
        const int grow = row0 + r;
        float y[8];
        #pragma unroll
        for (int c = 0; c < 8; ++c) y[c] = acc[c][r] + bias_v[c];
        float s1 = 0.f, s2 = 0.f;
        #pragma unroll
        for (int c = 0; c < 8; ++c) { s1 += y[c]; s2 = fmaf(y[c], y[c], s2); }
        #pragma unroll
        for (int d = 1; d < 16; d <<= 1) {
            s1 += __shfl_xor(s1, d);
            s2 += __shfl_xor(s2, d);
        }
        float mean = s1 * (1.0f / DIM);
        float var  = s2 * (1.0f / DIM) - mean * mean;
        float rstd = rsqrtf(var + 1e-5f);
        if (grow < NNODES) {
            float* op = out + (size_t)grow * DIM + m;
            #pragma unroll
            for (int c = 0; c < 8; ++c)
                op[16 * c] = fmaf((y[c] - mean) * rstd, g_v[c], bt_v[c]);
        }
    }
}

// ---------------------------------------------------------------------------
// samples = mean + eps*std; eps = jax.random.normal(key(42)), partitionable
// threefry: block inputs (0, i), bits = out0 ^ out1, key (0,42).
// ---------------------------------------------------------------------------
__device__ __forceinline__ unsigned rotl32(unsigned x, int r) {
    return (x << r) | (x >> (32 - r));
}

__device__ __forceinline__ unsigned threefry_xor(unsigned c0, unsigned c1) {
    const unsigned k0 = 0u, k1 = 42u;
    const unsigned k2 = k0 ^ k1 ^ 0x1BD11BDAu;
    unsigned x0 = c0 + k0;
    unsigned x1 = c1 + k1;
#define TF_ROUND(R) { x0 += x1; x1 = rotl32(x1, R); x1 ^= x0; }
    TF_ROUND(13) TF_ROUND(15) TF_ROUND(26) TF_ROUND(6)
    x0 += k1; x1 += k2 + 1u;
    TF_ROUND(17) TF_ROUND(29) TF_ROUND(16) TF_ROUND(24)
    x0 += k2; x1 += k0 + 2u;
    TF_ROUND(13) TF_ROUND(15) TF_ROUND(26) TF_ROUND(6)
    x0 += k0; x1 += k1 + 3u;
    TF_ROUND(17) TF_ROUND(29) TF_ROUND(16) TF_ROUND(24)
    x0 += k1; x1 += k2 + 4u;
    TF_ROUND(13) TF_ROUND(15) TF_ROUND(26) TF_ROUND(6)
    x0 += k2; x1 += k0 + 5u;
#undef TF_ROUND
    return x0 ^ x1;
}

__device__ __forceinline__ float bits_to_normal(unsigned bits) {
    float f = __uint_as_float((bits >> 9) | 0x3F800000u) - 1.0f;
    const float lo = -0.99999994f;
    float u = __fadd_rn(__fmul_rn(f, 2.0f), lo);
    u = fmaxf(lo, u);
    float w = -log1pf(-(u * u));
    float p;
    if (w < 5.0f) {
        w -= 2.5f;
        p = 2.81022636e-08f;
        p = fmaf(p, w, 3.43273939e-07f);
        p = fmaf(p, w, -3.5233877e-06f);
        p = fmaf(p, w, -4.39150654e-06f);
        p = fmaf(p, w, 0.00021858087f);
        p = fmaf(p, w, -0.00125372503f);
        p = fmaf(p, w, -0.00417768164f);
        p = fmaf(p, w, 0.246640727f);
        p = fmaf(p, w, 1.50140941f);
    } else {
        w = sqrtf(w) - 3.0f;
        p = -0.000200214257f;
        p = fmaf(p, w, 0.000100950558f);
        p = fmaf(p, w, 0.00134934322f);
        p = fmaf(p, w, -0.00367342844f);
        p = fmaf(p, w, 0.00573950773f);
        p = fmaf(p, w, -0.0076224613f);
        p = fmaf(p, w, 0.00943887047f);
        p = fmaf(p, w, 1.00167406f);
        p = fmaf(p, w, 2.83297682f);
    }
    return 1.41421356f * (p * u);
}

__global__ __launch_bounds__(TPB) void samples_kernel(
    const float* __restrict__ mean_v, const float* __restrict__ std_v,
    float* __restrict__ samples)
{
    int t = blockIdx.x * TPB + threadIdx.x;
    if (t >= NHID / 4) return;
    float4 m = ((const float4*)mean_v)[t];
    float4 s = ((const float4*)std_v)[t];
    float e[4];
    #pragma unroll
    for (int q = 0; q < 4; q++) {
        unsigned i = 4u * (unsigned)t + (unsigned)q;
        e[q] = bits_to_normal(threefry_xor(0u, i));
    }
    float4 r;
    r.x = fmaf(e[0], s.x, m.x);
    r.y = fmaf(e[1], s.y, m.y);
    r.z = fmaf(e[2], s.z, m.z);
    r.w = fmaf(e[3], s.w, m.w);
    ((float4*)samples)[t] = r;
}

// ---------------------------------------------------------------------------
// Orchestration (layer-interleaved paths, concatenated h, preconv weights):
//   memset -> convert_weights -> CSR build -> L0 f32 gather ->
//   fused0 -> [gather_cat -> fused_l] x2 -> final_proj -> samples.
//   14 dispatches. Buffers: h_cat = S (25.6MB bf16), acat = M..V (51.2MB
//   f32, dead before final writes M/V), samples -> S (h_cat dead).
//   d_ws: gcnt[196]|start[197]|bcur[196]|off[50001]|bucket[NE]|wpre[14 mats]
//   (wpre skipped w/ in-kernel fallback if ws_size too small).
// ---------------------------------------------------------------------------
extern "C" void kernel_launch(void* const* d_in, const int* in_sizes, int n_in,
                              void* d_out, int out_size, void* d_ws, size_t ws_size,
                              hipStream_t stream)
{
    const float* x     = (const float*)d_in[0];
    const int*   esrc  = (const int*)d_in[1];
    const int*   edst  = (const int*)d_in[2];
    const float* prm[2][7];
    for (int p = 0; p < 2; p++)
        for (int i = 0; i < 7; i++)
            prm[p][i] = (const float*)d_in[3 + p * 7 + i];
    const float* gamma = (const float*)d_in[17];
    const float* beta  = (const float*)d_in[18];

    float*  S  = (float*)d_out;
    float*  M  = S + NHID;
    float*  V  = M + NHID;
    bf16_t* Hc = (bf16_t*)S;     // h_cat [50000][256] bf16 = 25.6 MB
    float*  ACAT = M;            // [50000][256] f32 spans M..V = 51.2 MB

    int* gcnt  = (int*)d_ws;                       // NBINS
    int* start = gcnt + NBINS;                     // NBINS + 1
    int* bcur  = start + NBINS + 1;                // NBINS
    int* off   = bcur + NBINS;                     // NNODES + 1
    unsigned* bucket = (unsigned*)(off + NNODES + 1);  // NEDGES

    size_t csr_bytes = ((char*)(bucket + NEDGES)) - (char*)d_ws;
    size_t wpre_off  = (csr_bytes + 15) & ~(size_t)15;
    size_t need      = wpre_off + (size_t)NWMAT * WMAT * sizeof(bf16_t);
    bf16_t* wpre = (ws_size >= need) ? (bf16_t*)((char*)d_ws + wpre_off) : nullptr;

    const dim3 gChunk(NCHUNKS);
    const dim3 gBin(NBINS);
    const dim3 gGather((NNODES + (TPB / 64) - 1) / (TPB / 64));
    const dim3 gTile2(2 * NTILES);
    const dim3 gSamp((NHID / 4 + TPB - 1) / TPB);

    hipMemsetAsync(gcnt, 0, NBINS * sizeof(int), stream);
    if (wpre)
        convert_weights_kernel<<<dim3(NWMAT), TPB, 0, stream>>>(
            prm[0][0], prm[0][2], prm[0][5], prm[1][0], prm[1][2], prm[1][5], wpre);
    bin_hist_kernel<<<gChunk, TPB, 0, stream>>>(edst, gcnt);
    bin_scan_kernel<<<1, 64, 0, stream>>>(gcnt, start, bcur, off);
    bin_scatter_kernel<<<gChunk, TPB, 0, stream>>>(esrc, edst, bcur, bucket);
    build_csr_kernel<<<gBin, TPB, 0, stream>>>(start, bucket, off);

    // shared layer-0 aggregation (fp32 x) -> acat mean-half
    gather_agg_f32_kernel<<<gGather, TPB, 0, stream>>>(x, off, bucket, ACAT);

    // layer 0, both paths: z = (1+eps)*x + agg0 -> h_cat halves
    fused_layer_kernel<float, DIM><<<gTile2, TPB, 0, stream>>>(
        x, ACAT, 0, prm[0][4], prm[1][4], 0,
        prm[0][0], prm[0][1], prm[0][2], prm[0][3],
        prm[1][0], prm[1][1], prm[1][2], prm[1][3], wpre, Hc);

    for (int l = 1; l < 3; l++) {
        gather_cat_kernel<<<gGather, TPB, 0, stream>>>(Hc, off, bucket, ACAT);
        fused_layer_kernel<bf16_t, 256><<<gTile2, TPB, 0, stream>>>(
            Hc, ACAT, 1, prm[0][4], prm[1][4], l,
            prm[0][0] + (size_t)l * DIM * DIM, prm[0][1] + l * DIM,
            prm[0][2] + (size_t)l * DIM * DIM, prm[0][3] + l * DIM,
            prm[1][0] + (size_t)l * DIM * DIM, prm[1][1] + l * DIM,
            prm[1][2] + (size_t)l * DIM * DIM, prm[1][3] + l * DIM, wpre, Hc);
    }

    final_proj_kernel<<<gTile2, TPB, 0, stream>>>(
        Hc, prm[0][5], prm[0][6], prm[1][5], prm[1][6], gamma, beta, wpre, M, V);

    samples_kernel<<<gSamp, TPB, 0, stream>>>(M, V, S);
}

// Round 9
// 640.125 us; speedup vs baseline: 1.0066x; 1.0066x over previous
//
#include <hip/hip_runtime.h>
#include <math.h>

#define NNODES 50000
#define NEDGES 1600000
#define DIM    128
#define NHID   (NNODES * DIM)      // 6,400,000
#define TPB    256
#define NTILES ((NNODES + 63) / 64)   // 782, 64 rows per block-tile

// binned CSR build
#define NBINS  196                 // ceil(50000/256)
#define BINSZ  256                 // nodes per bin (dst>>8)
#define EPT    16                  // edges per thread in binning passes
#define CHUNK  (TPB * EPT)         // 4096 edges per block
#define NCHUNKS ((NEDGES + CHUNK - 1) / CHUNK)   // 391
#define BINCAP 10240               // staged edges per bin (mean 8192, sigma 90)

#define WMAT   (128 * 136)         // one padded W^T matrix (bf16 elems)
#define NWMAT  14                  // 2 paths x (3xW1 + 3xW2 + Wo)

typedef unsigned short bf16_t;
typedef __attribute__((ext_vector_type(8))) short short8;   // 8 bf16, 4 VGPRs
typedef __attribute__((ext_vector_type(4))) float f32x4;    // MFMA acc
typedef __attribute__((ext_vector_type(2))) float f32x2;

__device__ __forceinline__ float bf_lo(unsigned u) { return __uint_as_float(u << 16); }
__device__ __forceinline__ float bf_hi(unsigned u) { return __uint_as_float(u & 0xFFFF0000u); }
__device__ __forceinline__ bf16_t f2bf(float f) {   // RNE
    unsigned u = __float_as_uint(f);
    u += 0x7FFFu + ((u >> 16) & 1u);
    return (bf16_t)(u >> 16);
}
__device__ __forceinline__ unsigned pack2bf(float a, float b) {
    return (unsigned)f2bf(a) | ((unsigned)f2bf(b) << 16);
}

union S8U { short8 v; uint4 u4; unsigned us[4]; };

// ===========================================================================
// CSR build, dense-write pipeline (round-2 proven):
//   bin_hist -> bin_scan -> bin_scatter (packed dl<<16|src) -> build_csr
//   (per-bin LDS counting sort -> per-node off[] + sorted src bucket).
// ===========================================================================
__global__ __launch_bounds__(TPB) void bin_hist_kernel(
    const int* __restrict__ dst, int* __restrict__ gcnt)
{
    __shared__ int lcnt[NBINS];
    const int tid = threadIdx.x;
    for (int i = tid; i < NBINS; i += TPB) lcnt[i] = 0;
    __syncthreads();
    const int base = blockIdx.x * CHUNK;
    #pragma unroll
    for (int k = 0; k < EPT; ++k) {
        int e = base + k * TPB + tid;
        if (e < NEDGES) atomicAdd(&lcnt[dst[e] >> 8], 1);
    }
    __syncthreads();
    for (int i = tid; i < NBINS; i += TPB) {
        int c = lcnt[i];
        if (c) atomicAdd(&gcnt[i], c);
    }
}

__global__ __launch_bounds__(64) void bin_scan_kernel(
    const int* __restrict__ gcnt, int* __restrict__ start, int* __restrict__ bcur,
    int* __restrict__ off)
{
    const int lane = threadIdx.x;   // 64 lanes, each owns 4 bins
    int c[4];
    int s = 0;
    #pragma unroll
    for (int k = 0; k < 4; ++k) {
        int b = 4 * lane + k;
        c[k] = (b < NBINS) ? gcnt[b] : 0;
        s += c[k];
    }
    int incl = s;
    #pragma unroll
    for (int d = 1; d < 64; d <<= 1) {
        int t = __shfl_up(incl, d);
        if (lane >= d) incl += t;
    }
    int excl = incl - s;
    #pragma unroll
    for (int k = 0; k < 4; ++k) {
        int b = 4 * lane + k;
        if (b < NBINS) { start[b] = excl; bcur[b] = excl; }
        excl += c[k];
    }
    if (lane == 63) { start[NBINS] = excl; off[NNODES] = excl; }   // == NEDGES
}

__global__ __launch_bounds__(TPB) void bin_scatter_kernel(
    const int* __restrict__ src, const int* __restrict__ dst,
    int* __restrict__ bcur, unsigned* __restrict__ bucket)
{
    __shared__ int lcnt[NBINS];    // phase A: counts
    __shared__ int lcur[NBINS];    // phase C: absolute cursors
    const int tid = threadIdx.x;
    for (int i = tid; i < NBINS; i += TPB) lcnt[i] = 0;
    __syncthreads();

    unsigned pk[EPT];
    int bn[EPT];
    const int base = blockIdx.x * CHUNK;
    #pragma unroll
    for (int k = 0; k < EPT; ++k) {
        int e = base + k * TPB + tid;
        int b = -1; unsigned p = 0;
        if (e < NEDGES) {
            int d = dst[e];
            int s = src[e];
            b = d >> 8;
            p = ((unsigned)(d & 255) << 16) | (unsigned)s;
            atomicAdd(&lcnt[b], 1);
        }
        pk[k] = p; bn[k] = b;
    }
    __syncthreads();
    for (int i = tid; i < NBINS; i += TPB) {
        int c = lcnt[i];
        lcur[i] = (c > 0) ? atomicAdd(&bcur[i], c) : 0;
    }
    __syncthreads();
    #pragma unroll
    for (int k = 0; k < EPT; ++k) {
        if (bn[k] >= 0) {
            int p = atomicAdd(&lcur[bn[k]], 1);
            bucket[p] = pk[k];
        }
    }
}

__global__ __launch_bounds__(TPB) void build_csr_kernel(
    const int* __restrict__ start, unsigned* __restrict__ bucket,
    int* __restrict__ off)
{
    __shared__ unsigned se[BINCAP];   // staged bin edges, 40 KB
    __shared__ int lcnt[BINSZ];
    __shared__ int lofs[BINSZ];
    __shared__ int wsum[4];
    const int tid = threadIdx.x;
    const int b = blockIdx.x;
    const int j0 = start[b], j1 = start[b + 1];
    const int n = j1 - j0;            // <= BINCAP by construction

    lcnt[tid] = 0;
    for (int i = tid; i < n; i += TPB) se[i] = bucket[j0 + i];
    __syncthreads();
    for (int i = tid; i < n; i += TPB) atomicAdd(&lcnt[se[i] >> 16], 1);
    __syncthreads();

    // exclusive scan of lcnt[256] across 4 waves
    const int lane = tid & 63, wid = tid >> 6;
    int v = lcnt[tid];
    int s = v;
    #pragma unroll
    for (int d = 1; d < 64; d <<= 1) {
        int t = __shfl_up(s, d);
        if (lane >= d) s += t;
    }
    if (lane == 63) wsum[wid] = s;
    __syncthreads();
    if (tid == 0) {
        int a = 0;
        #pragma unroll
        for (int k = 0; k < 4; ++k) { int t = wsum[k]; wsum[k] = a; a += t; }
    }
    __syncthreads();
    int excl = wsum[wid] + s - v;
    lofs[tid] = excl;
    int node = b * BINSZ + tid;
    if (node < NNODES) off[node] = j0 + excl;
    __syncthreads();

    // in-place counting-sort scatter (safe: all edges staged in LDS)
    for (int i = tid; i < n; i += TPB) {
        unsigned e = se[i];
        int pos = atomicAdd(&lofs[e >> 16], 1);
        bucket[j0 + pos] = e & 0xFFFFu;   // src node id
    }
}

// ---------------------------------------------------------------------------
// One-time weight preconversion: all 14 matrices -> bf16 W^T in the exact
// padded [128][136] layout the LDS staging uses. Matrix b = p*7 + s,
// s: 0..2 = W1 layer, 3..5 = W2 layer, 6 = Wout.
// ---------------------------------------------------------------------------
__global__ __launch_bounds__(TPB) void convert_weights_kernel(
    const float* __restrict__ W1_0, const float* __restrict__ W2_0,
    const float* __restrict__ Wo_0,
    const float* __restrict__ W1_1, const float* __restrict__ W2_1,
    const float* __restrict__ Wo_1,
    bf16_t* __restrict__ wpre)
{
    const int b = blockIdx.x;
    const int p = b / 7, s = b % 7;
    const float* W;
    if (s < 3)      W = (p ? W1_1 : W1_0) + (size_t)s * DIM * DIM;
    else if (s < 6) W = (p ? W2_1 : W2_0) + (size_t)(s - 3) * DIM * DIM;
    else            W = p ? Wo_1 : Wo_0;
    bf16_t* dst = wpre + (size_t)b * WMAT;

    for (int idx = threadIdx.x; idx < 128 * 16; idx += TPB) {
        int n = idx & 127, koct = idx >> 7;
        float f[8];
        #pragma unroll
        for (int j = 0; j < 8; ++j) f[j] = W[(8 * koct + j) * 128 + n];
        uint4 u;
        u.x = pack2bf(f[0], f[1]); u.y = pack2bf(f[2], f[3]);
        u.z = pack2bf(f[4], f[5]); u.w = pack2bf(f[6], f[7]);
        *(uint4*)&dst[n * 136 + 8 * koct] = u;
    }
}

// ---------------------------------------------------------------------------
// Gather aggregation, wave per node, 16/8/1-deep ILP.
// acat output stores are NON-TEMPORAL: 25-50 MB of streamed writes per
// dispatch must not write-allocate in L2 (would evict the randomly-hit
// h_cat rows that give the observed ~58% hit rate).
// ---------------------------------------------------------------------------
__global__ __launch_bounds__(TPB) void gather_agg_f32_kernel(
    const float* __restrict__ h, const int* __restrict__ off,
    const unsigned* __restrict__ bucket, float* __restrict__ acat)
{
    int node = blockIdx.x * (TPB / 64) + (threadIdx.x >> 6);
    int lane = threadIdx.x & 63;
    if (node >= NNODES) return;
    int j0 = off[node], j1 = off[node + 1];
    const float* base = h + 2 * lane;
    float ax = 0.0f, ay = 0.0f;
    int j = j0;
    for (; j + 16 <= j1; j += 16) {
        unsigned s[16];
        #pragma unroll
        for (int k = 0; k < 16; ++k) s[k] = bucket[j + k];
        float2 v[16];
        #pragma unroll
        for (int k = 0; k < 16; ++k) v[k] = *(const float2*)(base + (size_t)s[k] * DIM);
        #pragma unroll
        for (int k = 0; k < 16; ++k) { ax += v[k].x; ay += v[k].y; }
    }
    for (; j + 8 <= j1; j += 8) {
        unsigned s[8];
        #pragma unroll
        for (int k = 0; k < 8; ++k) s[k] = bucket[j + k];
        float2 v[8];
        #pragma unroll
        for (int k = 0; k < 8; ++k) v[k] = *(const float2*)(base + (size_t)s[k] * DIM);
        #pragma unroll
        for (int k = 0; k < 8; ++k) { ax += v[k].x; ay += v[k].y; }
    }
    for (; j < j1; ++j) {
        float2 v0 = *(const float2*)(base + (size_t)bucket[j] * DIM);
        ax += v0.x; ay += v0.y;
    }
    f32x2 r; r.x = ax; r.y = ay;
    __builtin_nontemporal_store(r, (f32x2*)(acat + (size_t)node * 256 + 2 * lane));
}

__global__ __launch_bounds__(TPB) void gather_cat_kernel(
    const bf16_t* __restrict__ hc, const int* __restrict__ off,
    const unsigned* __restrict__ bucket, float* __restrict__ acat)
{
    int node = blockIdx.x * (TPB / 64) + (threadIdx.x >> 6);
    int lane = threadIdx.x & 63;
    if (node >= NNODES) return;
    int j0 = off[node], j1 = off[node + 1];
    const uint2* base = (const uint2*)hc + lane;   // 64 uint2 per 512B row
    float a0 = 0.f, a1 = 0.f, a2 = 0.f, a3 = 0.f;
    int j = j0;
    for (; j + 16 <= j1; j += 16) {
        unsigned s[16];
        #pragma unroll
        for (int k = 0; k < 16; ++k) s[k] = bucket[j + k];
        uint2 u[16];
        #pragma unroll
        for (int k = 0; k < 16; ++k) u[k] = base[(size_t)s[k] * 64];
        #pragma unroll
        for (int k = 0; k < 16; ++k) {
            a0 += bf_lo(u[k].x); a1 += bf_hi(u[k].x);
            a2 += bf_lo(u[k].y); a3 += bf_hi(u[k].y);
        }
    }
    for (; j + 8 <= j1; j += 8) {
        unsigned s[8];
        #pragma unroll
        for (int k = 0; k < 8; ++k) s[k] = bucket[j + k];
        uint2 u[8];
        #pragma unroll
        for (int k = 0; k < 8; ++k) u[k] = base[(size_t)s[k] * 64];
        #pragma unroll
        for (int k = 0; k < 8; ++k) {
            a0 += bf_lo(u[k].x); a1 += bf_hi(u[k].x);
            a2 += bf_lo(u[k].y); a3 += bf_hi(u[k].y);
        }
    }
    for (; j < j1; ++j) {
        uint2 u = base[(size_t)bucket[j] * 64];
        a0 += bf_lo(u.x); a1 += bf_hi(u.x);
        a2 += bf_lo(u.y); a3 += bf_hi(u.y);
    }
    // lane<32: mean cols 4l..4l+3 -> acat[4l..]; lane>=32: std cols -> 128+...
    f32x4 r; r.x = a0; r.y = a1; r.z = a2; r.w = a3;
    __builtin_nontemporal_store(r, (f32x4*)(acat + (size_t)node * 256 + 4 * lane));
}

// ---------------------------------------------------------------------------
// FUSED GIN layer v3 (round-7 structure + preconverted weights):
//   out_half = sigmoid(z@W1+b1)@W2+b2, z = (1+eps)*hin_half + agg_half.
//   ONE W LDS buffer (W1 then W2) + bf16 y1 = 52.2 KB -> 3 blocks/CU;
//   W staging = pure uint4 memcpy from wpre (fallback: in-kernel convert).
//   __launch_bounds__(TPB,4) caps VGPR at 128 -> 12 waves/CU.
// ---------------------------------------------------------------------------
template <class HinT, int INSTRIDE>
__global__ __launch_bounds__(TPB, 4) void fused_layer_kernel(
    const HinT* __restrict__ hin, const float* __restrict__ acat, int aggByPath,
    const float* __restrict__ eps0, const float* __restrict__ eps1, int eps_idx,
    const float* __restrict__ W1_0, const float* __restrict__ b1_0,
    const float* __restrict__ W2_0, const float* __restrict__ b2_0,
    const float* __restrict__ W1_1, const float* __restrict__ b1_1,
    const float* __restrict__ W2_1, const float* __restrict__ b2_1,
    const bf16_t* __restrict__ wpre,
    bf16_t* __restrict__ out)
{
    __shared__ short sWt[128 * 136];   // 34.8 KB: W1^T, then W2^T
    __shared__ short y1b[64 * 136];    // 17.4 KB: bf16 y1

    const int p = (blockIdx.x >= NTILES) ? 1 : 0;
    const int t = blockIdx.x - p * NTILES;
    const int l = eps_idx;
    const float* W1 = p ? W1_1 : W1_0;
    const float* b1 = p ? b1_1 : b1_0;
    const float* W2 = p ? W2_1 : W2_0;
    const float* b2 = p ? b2_1 : b2_0;
    const float* epsp = p ? eps1 : eps0;
    const HinT* hbase = (INSTRIDE == 256) ? (hin + p * 128) : hin;
    const float* abase = acat + (aggByPath ? p * 128 : 0);
    bf16_t* ob = out + p * 128;

    const int tid = threadIdx.x;
    // ---- stage W1^T ----
    if (wpre) {
        const uint4* s = (const uint4*)(wpre + (size_t)(p * 7 + l) * WMAT);
        uint4* d = (uint4*)sWt;
        #pragma unroll
        for (int i = 0; i < 9; ++i) {
            int idx = i * 256 + tid;
            if (idx < WMAT / 8) d[idx] = s[idx];
        }
    } else {
        #pragma unroll
        for (int it = 0; it < 8; ++it) {
            int idx = it * 256 + tid;
            int n = idx & 127, koct = idx >> 7;
            float f1[8];
            #pragma unroll
            for (int j = 0; j < 8; ++j) f1[j] = W1[(8 * koct + j) * 128 + n];
            uint4 u1;
            u1.x = pack2bf(f1[0], f1[1]); u1.y = pack2bf(f1[2], f1[3]);
            u1.z = pack2bf(f1[4], f1[5]); u1.w = pack2bf(f1[6], f1[7]);
            *(uint4*)&sWt[n * 136 + 8 * koct] = u1;
        }
    }
    __syncthreads();

    const int lane = tid & 63, w = tid >> 6;
    const int m = lane & 15, quad = lane >> 4;

    const float scale = 1.0f + epsp[eps_idx];
    float b1v[8], b2v[8];
    #pragma unroll
    for (int c = 0; c < 8; ++c) { b1v[c] = b1[16 * c + m]; b2v[c] = b2[16 * c + m]; }

    const int arow = min(t * 64 + 16 * w + m, NNODES - 1);

    // ---- A-fragments: z = scale*hin + agg, hi/lo split ----
    short8 afh[4], afl[4];
    #pragma unroll
    for (int k0 = 0; k0 < 4; ++k0) {
        const int kb = 32 * k0 + 8 * quad;
        float zf[8];
        if constexpr (sizeof(HinT) == 4) {
            const float* hp = (const float*)hbase + (size_t)arow * INSTRIDE + kb;
            float4 h0 = *(const float4*)hp;
            float4 h1 = *(const float4*)(hp + 4);
            zf[0] = h0.x; zf[1] = h0.y; zf[2] = h0.z; zf[3] = h0.w;
            zf[4] = h1.x; zf[5] = h1.y; zf[6] = h1.z; zf[7] = h1.w;
        } else {
            uint4 hu = *(const uint4*)((const bf16_t*)hbase + (size_t)arow * INSTRIDE + kb);
            zf[0] = bf_lo(hu.x); zf[1] = bf_hi(hu.x);
            zf[2] = bf_lo(hu.y); zf[3] = bf_hi(hu.y);
            zf[4] = bf_lo(hu.z); zf[5] = bf_hi(hu.z);
            zf[6] = bf_lo(hu.w); zf[7] = bf_hi(hu.w);
        }
        const float* ap = abase + (size_t)arow * 256 + kb;
        float4 a0 = *(const float4*)ap;
        float4 a1 = *(const float4*)(ap + 4);
        zf[0] = fmaf(scale, zf[0], a0.x); zf[1] = fmaf(scale, zf[1], a0.y);
        zf[2] = fmaf(scale, zf[2], a0.z); zf[3] = fmaf(scale, zf[3], a0.w);
        zf[4] = fmaf(scale, zf[4], a1.x); zf[5] = fmaf(scale, zf[5], a1.y);
        zf[6] = fmaf(scale, zf[6], a1.z); zf[7] = fmaf(scale, zf[7], a1.w);
        S8U hi;
        hi.us[0] = pack2bf(zf[0], zf[1]); hi.us[1] = pack2bf(zf[2], zf[3]);
        hi.us[2] = pack2bf(zf[4], zf[5]); hi.us[3] = pack2bf(zf[6], zf[7]);
        afh[k0] = hi.v;
        S8U lo;
        float lw[8];
        lw[0] = zf[0] - bf_lo(hi.us[0]); lw[1] = zf[1] - bf_hi(hi.us[0]);
        lw[2] = zf[2] - bf_lo(hi.us[1]); lw[3] = zf[3] - bf_hi(hi.us[1]);
        lw[4] = zf[4] - bf_lo(hi.us[2]); lw[5] = zf[5] - bf_hi(hi.us[2]);
        lw[6] = zf[6] - bf_lo(hi.us[3]); lw[7] = zf[7] - bf_hi(hi.us[3]);
        lo.us[0] = pack2bf(lw[0], lw[1]); lo.us[1] = pack2bf(lw[2], lw[3]);
        lo.us[2] = pack2bf(lw[4], lw[5]); lo.us[3] = pack2bf(lw[6], lw[7]);
        afl[k0] = lo.v;
    }

    // ---- MFMA1: B-frags from LDS (read once per (k0,c), used twice) ----
    f32x4 acc[8];
    #pragma unroll
    for (int c = 0; c < 8; ++c) acc[c] = (f32x4){0.f, 0.f, 0.f, 0.f};
    #pragma unroll
    for (int k0 = 0; k0 < 4; ++k0) {
        const int kb = 32 * k0 + 8 * quad;
        #pragma unroll
        for (int c = 0; c < 8; ++c) {
            short8 bfr = *(const short8*)&sWt[(16 * c + m) * 136 + kb];
            acc[c] = __builtin_amdgcn_mfma_f32_16x16x32_bf16(afl[k0], bfr, acc[c], 0, 0, 0);
            acc[c] = __builtin_amdgcn_mfma_f32_16x16x32_bf16(afh[k0], bfr, acc[c], 0, 0, 0);
        }
    }

    // ---- sigmoid + stage y1 as bf16 ----
    const int rloc0 = 16 * w + 4 * quad;   // local row in [0,64)
    #pragma unroll
    for (int r = 0; r < 4; ++r) {
        #pragma unroll
        for (int c = 0; c < 8; ++c) {
            float y = acc[c][r] + b1v[c];
            y = 1.0f / (1.0f + expf(-y));
            y1b[(rloc0 + r) * 136 + 16 * c + m] = (short)f2bf(y);
        }
    }
    __syncthreads();   // MFMA1 sWt reads + y1 writes complete

    // ---- stage W2^T into the same buffer ----
    if (wpre) {
        const uint4* s = (const uint4*)(wpre + (size_t)(p * 7 + 3 + l) * WMAT);
        uint4* d = (uint4*)sWt;
        #pragma unroll
        for (int i = 0; i < 9; ++i) {
            int idx = i * 256 + tid;
            if (idx < WMAT / 8) d[idx] = s[idx];
        }
    } else {
        #pragma unroll
        for (int it = 0; it < 8; ++it) {
            int idx = it * 256 + tid;
            int n = idx & 127, koct = idx >> 7;
            float f2[8];
            #pragma unroll
            for (int j = 0; j < 8; ++j) f2[j] = W2[(8 * koct + j) * 128 + n];
            uint4 u2;
            u2.x = pack2bf(f2[0], f2[1]); u2.y = pack2bf(f2[2], f2[3]);
            u2.z = pack2bf(f2[4], f2[5]); u2.w = pack2bf(f2[6], f2[7]);
            *(uint4*)&sWt[n * 136 + 8 * koct] = u2;
        }
    }
    __syncthreads();

    // ---- MFMA2: A from y1b (bf16 direct), B from sWt ----
    f32x4 acc2[8];
    #pragma unroll
    for (int c = 0; c < 8; ++c) acc2[c] = (f32x4){0.f, 0.f, 0.f, 0.f};
    #pragma unroll
    for (int k0 = 0; k0 < 4; ++k0) {
        const int kb = 32 * k0 + 8 * quad;
        short8 a2 = *(const short8*)&y1b[(16 * w + m) * 136 + kb];
        #pragma unroll
        for (int c = 0; c < 8; ++c) {
            short8 b2f = *(const short8*)&sWt[(16 * c + m) * 136 + kb];
            acc2[c] = __builtin_amdgcn_mfma_f32_16x16x32_bf16(a2, b2f, acc2[c], 0, 0, 0);
        }
    }

    // ---- epilogue: h_out = acc2 + b2 (bf16, stride 256) ----
    const int row0 = t * 64 + 16 * w + 4 * quad;
    #pragma unroll
    for (int r = 0; r < 4; ++r) {
        const int grow = row0 + r;
        if (grow < NNODES) {
            bf16_t* op = ob + (size_t)grow * 256 + m;
            #pragma unroll
            for (int c = 0; c < 8; ++c) op[16 * c] = f2bf(acc2[c][r] + b2v[c]);
        }
    }
}

// ---------------------------------------------------------------------------
// Final projection + layernorm, both paths in one grid:
//   out(p) = layernorm(h_cat(p) @ Wout + bout) * gamma + beta  (fp32)
// ---------------------------------------------------------------------------
__global__ __launch_bounds__(TPB) void final_proj_kernel(
    const bf16_t* __restrict__ hc,
    const float* __restrict__ Wo0, const float* __restrict__ bo0,
    const float* __restrict__ Wo1, const float* __restrict__ bo1,
    const float* __restrict__ gamma, const float* __restrict__ beta,
    const bf16_t* __restrict__ wpre,
    float* __restrict__ M, float* __restrict__ V)
{
    __shared__ short sWt[128 * 136];   // bf16 W^T

    const int p = (blockIdx.x >= NTILES) ? 1 : 0;
    const int t = blockIdx.x - p * NTILES;
    const float* W = p ? Wo1 : Wo0;
    const float* bias = p ? bo1 : bo0;
    const bf16_t* hbase = hc + p * 128;
    float* out = p ? V : M;

    const int tid = threadIdx.x;
    if (wpre) {
        const uint4* s = (const uint4*)(wpre + (size_t)(p * 7 + 6) * WMAT);
        uint4* d = (uint4*)sWt;
        #pragma unroll
        for (int i = 0; i < 9; ++i) {
            int idx = i * 256 + tid;
            if (idx < WMAT / 8) d[idx] = s[idx];
        }
    } else {
        #pragma unroll
        for (int it = 0; it < 8; ++it) {
            int idx = it * 256 + tid;
            int n = idx & 127, koct = idx >> 7;
            float f[8];
            #pragma unroll
            for (int j = 0; j < 8; ++j) f[j] = W[(8 * koct + j) * 128 + n];
            uint4 u;
            u.x = pack2bf(f[0], f[1]); u.y = pack2bf(f[2], f[3]);
            u.z = pack2bf(f[4], f[5]); u.w = pack2bf(f[6], f[7]);
            *(uint4*)&sWt[n * 136 + 8 * koct] = u;
        }
    }
    __syncthreads();

    const int lane = tid & 63, w = tid >> 6;
    const int m = lane & 15, quad = lane >> 4;

    short8 bf[32];
    #pragma unroll
    for (int c = 0; c < 8; ++c)
        #pragma unroll
        for (int k0 = 0; k0 < 4; ++k0)
            bf[c * 4 + k0] = *(const short8*)&sWt[(16 * c + m) * 136 + 32 * k0 + 8 * quad];

    float bias_v[8], g_v[8], bt_v[8];
    #pragma unroll
    for (int c = 0; c < 8; ++c) {
        bias_v[c] = bias[16 * c + m];
        g_v[c] = gamma[16 * c + m];
        bt_v[c] = beta[16 * c + m];
    }

    const int arow = min(t * 64 + 16 * w + m, NNODES - 1);
    short8 af[4];
    #pragma unroll
    for (int k0 = 0; k0 < 4; ++k0)
        af[k0] = *(const short8*)(hbase + (size_t)arow * 256 + 32 * k0 + 8 * quad);

    f32x4 acc[8];
    #pragma unroll
    for (int c = 0; c < 8; ++c) acc[c] = (f32x4){0.f, 0.f, 0.f, 0.f};
    #pragma unroll
    for (int k0 = 0; k0 < 4; ++k0)
        #pragma unroll
        for (int c = 0; c < 8; ++c)
            acc[c] = __builtin_amdgcn_mfma_f32_16x16x32_bf16(
                af[k0], bf[c * 4 + k0], acc[c], 0, 0, 0);

    const int row0 = t * 64 + 16 * w + 4 * quad;
    #pragma unroll
    for (int r = 0; r < 4; ++r) {
        const int grow = row0 + r;
        float y[8];
        #pragma unroll
        for (int c = 0; c < 8; ++c) y[c] = acc[c][r] + bias_v[c];
        float s1 = 0.f, s2 = 0.f;
        #pragma unroll
        for (int c = 0; c < 8; ++c) { s1 += y[c]; s2 = fmaf(y[c], y[c], s2); }
        #pragma unroll
        for (int d = 1; d < 16; d <<= 1) {
            s1 += __shfl_xor(s1, d);
            s2 += __shfl_xor(s2, d);
        }
        float mean = s1 * (1.0f / DIM);
        float var  = s2 * (1.0f / DIM) - mean * mean;
        float rstd = rsqrtf(var + 1e-5f);
        if (grow < NNODES) {
            float* op = out + (size_t)grow * DIM + m;
            #pragma unroll
            for (int c = 0; c < 8; ++c)
                op[16 * c] = fmaf((y[c] - mean) * rstd, g_v[c], bt_v[c]);
        }
    }
}

// ---------------------------------------------------------------------------
// samples = mean + eps*std; eps = jax.random.normal(key(42)), partitionable
// threefry: block inputs (0, i), bits = out0 ^ out1, key (0,42).
// ---------------------------------------------------------------------------
__device__ __forceinline__ unsigned rotl32(unsigned x, int r) {
    return (x << r) | (x >> (32 - r));
}

__device__ __forceinline__ unsigned threefry_xor(unsigned c0, unsigned c1) {
    const unsigned k0 = 0u, k1 = 42u;
    const unsigned k2 = k0 ^ k1 ^ 0x1BD11BDAu;
    unsigned x0 = c0 + k0;
    unsigned x1 = c1 + k1;
#define TF_ROUND(R) { x0 += x1; x1 = rotl32(x1, R); x1 ^= x0; }
    TF_ROUND(13) TF_ROUND(15) TF_ROUND(26) TF_ROUND(6)
    x0 += k1; x1 += k2 + 1u;
    TF_ROUND(17) TF_ROUND(29) TF_ROUND(16) TF_ROUND(24)
    x0 += k2; x1 += k0 + 2u;
    TF_ROUND(13) TF_ROUND(15) TF_ROUND(26) TF_ROUND(6)
    x0 += k0; x1 += k1 + 3u;
    TF_ROUND(17) TF_ROUND(29) TF_ROUND(16) TF_ROUND(24)
    x0 += k1; x1 += k2 + 4u;
    TF_ROUND(13) TF_ROUND(15) TF_ROUND(26) TF_ROUND(6)
    x0 += k2; x1 += k0 + 5u;
#undef TF_ROUND
    return x0 ^ x1;
}

__device__ __forceinline__ float bits_to_normal(unsigned bits) {
    float f = __uint_as_float((bits >> 9) | 0x3F800000u) - 1.0f;
    const float lo = -0.99999994f;
    float u = __fadd_rn(__fmul_rn(f, 2.0f), lo);
    u = fmaxf(lo, u);
    float w = -log1pf(-(u * u));
    float p;
    if (w < 5.0f) {
        w -= 2.5f;
        p = 2.81022636e-08f;
        p = fmaf(p, w, 3.43273939e-07f);
        p = fmaf(p, w, -3.5233877e-06f);
        p = fmaf(p, w, -4.39150654e-06f);
        p = fmaf(p, w, 0.00021858087f);
        p = fmaf(p, w, -0.00125372503f);
        p = fmaf(p, w, -0.00417768164f);
        p = fmaf(p, w, 0.246640727f);
        p = fmaf(p, w, 1.50140941f);
    } else {
        w = sqrtf(w) - 3.0f;
        p = -0.000200214257f;
        p = fmaf(p, w, 0.000100950558f);
        p = fmaf(p, w, 0.00134934322f);
        p = fmaf(p, w, -0.00367342844f);
        p = fmaf(p, w, 0.00573950773f);
        p = fmaf(p, w, -0.0076224613f);
        p = fmaf(p, w, 0.00943887047f);
        p = fmaf(p, w, 1.00167406f);
        p = fmaf(p, w, 2.83297682f);
    }
    return 1.41421356f * (p * u);
}

__global__ __launch_bounds__(TPB) void samples_kernel(
    const float* __restrict__ mean_v, const float* __restrict__ std_v,
    float* __restrict__ samples)
{
    int t = blockIdx.x * TPB + threadIdx.x;
    if (t >= NHID / 4) return;
    float4 m = ((const float4*)mean_v)[t];
    float4 s = ((const float4*)std_v)[t];
    float e[4];
    #pragma unroll
    for (int q = 0; q < 4; q++) {
        unsigned i = 4u * (unsigned)t + (unsigned)q;
        e[q] = bits_to_normal(threefry_xor(0u, i));
    }
    f32x4 r;
    r.x = fmaf(e[0], s.x, m.x);
    r.y = fmaf(e[1], s.y, m.y);
    r.z = fmaf(e[2], s.z, m.z);
    r.w = fmaf(e[3], s.w, m.w);
    __builtin_nontemporal_store(r, (f32x4*)samples + t);
}

// ---------------------------------------------------------------------------
// Orchestration (layer-interleaved paths, concatenated h, preconv weights):
//   memset -> convert_weights -> CSR build -> L0 f32 gather ->
//   fused0 -> [gather_cat -> fused_l] x2 -> final_proj -> samples.
//   14 dispatches. Buffers: h_cat = S (25.6MB bf16), acat = M..V (51.2MB
//   f32, dead before final writes M/V), samples -> S (h_cat dead).
//   d_ws: gcnt[196]|start[197]|bcur[196]|off[50001]|bucket[NE]|wpre[14 mats]
//   (wpre skipped w/ in-kernel fallback if ws_size too small).
// ---------------------------------------------------------------------------
extern "C" void kernel_launch(void* const* d_in, const int* in_sizes, int n_in,
                              void* d_out, int out_size, void* d_ws, size_t ws_size,
                              hipStream_t stream)
{
    const float* x     = (const float*)d_in[0];
    const int*   esrc  = (const int*)d_in[1];
    const int*   edst  = (const int*)d_in[2];
    const float* prm[2][7];
    for (int p = 0; p < 2; p++)
        for (int i = 0; i < 7; i++)
            prm[p][i] = (const float*)d_in[3 + p * 7 + i];
    const float* gamma = (const float*)d_in[17];
    const float* beta  = (const float*)d_in[18];

    float*  S  = (float*)d_out;
    float*  M  = S + NHID;
    float*  V  = M + NHID;
    bf16_t* Hc = (bf16_t*)S;     // h_cat [50000][256] bf16 = 25.6 MB
    float*  ACAT = M;            // [50000][256] f32 spans M..V = 51.2 MB

    int* gcnt  = (int*)d_ws;                       // NBINS
    int* start = gcnt + NBINS;                     // NBINS + 1
    int* bcur  = start + NBINS + 1;                // NBINS
    int* off   = bcur + NBINS;                     // NNODES + 1
    unsigned* bucket = (unsigned*)(off + NNODES + 1);  // NEDGES

    size_t csr_bytes = ((char*)(bucket + NEDGES)) - (char*)d_ws;
    size_t wpre_off  = (csr_bytes + 15) & ~(size_t)15;
    size_t need      = wpre_off + (size_t)NWMAT * WMAT * sizeof(bf16_t);
    bf16_t* wpre = (ws_size >= need) ? (bf16_t*)((char*)d_ws + wpre_off) : nullptr;

    const dim3 gChunk(NCHUNKS);
    const dim3 gBin(NBINS);
    const dim3 gGather((NNODES + (TPB / 64) - 1) / (TPB / 64));
    const dim3 gTile2(2 * NTILES);
    const dim3 gSamp((NHID / 4 + TPB - 1) / TPB);

    hipMemsetAsync(gcnt, 0, NBINS * sizeof(int), stream);
    if (wpre)
        convert_weights_kernel<<<dim3(NWMAT), TPB, 0, stream>>>(
            prm[0][0], prm[0][2], prm[0][5], prm[1][0], prm[1][2], prm[1][5], wpre);
    bin_hist_kernel<<<gChunk, TPB, 0, stream>>>(edst, gcnt);
    bin_scan_kernel<<<1, 64, 0, stream>>>(gcnt, start, bcur, off);
    bin_scatter_kernel<<<gChunk, TPB, 0, stream>>>(esrc, edst, bcur, bucket);
    build_csr_kernel<<<gBin, TPB, 0, stream>>>(start, bucket, off);

    // shared layer-0 aggregation (fp32 x) -> acat mean-half
    gather_agg_f32_kernel<<<gGather, TPB, 0, stream>>>(x, off, bucket, ACAT);

    // layer 0, both paths: z = (1+eps)*x + agg0 -> h_cat halves
    fused_layer_kernel<float, DIM><<<gTile2, TPB, 0, stream>>>(
        x, ACAT, 0, prm[0][4], prm[1][4], 0,
        prm[0][0], prm[0][1], prm[0][2], prm[0][3],
        prm[1][0], prm[1][1], prm[1][2], prm[1][3], wpre, Hc);

    for (int l = 1; l < 3; l++) {
        gather_cat_kernel<<<gGather, TPB, 0, stream>>>(Hc, off, bucket, ACAT);
        fused_layer_kernel<bf16_t, 256><<<gTile2, TPB, 0, stream>>>(
            Hc, ACAT, 1, prm[0][4], prm[1][4], l,
            prm[0][0] + (size_t)l * DIM * DIM, prm[0][1] + l * DIM,
            prm[0][2] + (size_t)l * DIM * DIM, prm[0][3] + l * DIM,
            prm[1][0] + (size_t)l * DIM * DIM, prm[1][1] + l * DIM,
            prm[1][2] + (size_t)l * DIM * DIM, prm[1][3] + l * DIM, wpre, Hc);
    }

    final_proj_kernel<<<gTile2, TPB, 0, stream>>>(
        Hc, prm[0][5], prm[0][6], prm[1][5], prm[1][6], gamma, beta, wpre, M, V);

    samples_kernel<<<gSamp, TPB, 0, stream>>>(M, V, S);
}

// Round 10
// 636.016 us; speedup vs baseline: 1.0131x; 1.0065x over previous
//
#include <hip/hip_runtime.h>
#include <math.h>

#define NNODES 50000
#define NEDGES 1600000
#define DIM    128
#define NHID   (NNODES * DIM)      // 6,400,000
#define TPB    256
#define NTILES ((NNODES + 63) / 64)   // 782, 64 rows per block-tile

// binned CSR build
#define NBINS  196                 // ceil(50000/256)
#define BINSZ  256                 // nodes per bin (dst>>8)
#define EPT    16                  // edges per thread in binning passes
#define CHUNK  (TPB * EPT)         // 4096 edges per block
#define NCHUNKS ((NEDGES + CHUNK - 1) / CHUNK)   // 391
#define BINCAP 10240               // fat-bin capacity (mean 8163, sigma ~90)

#define WMAT   (128 * 136)         // one padded W^T matrix (bf16 elems)
#define NWMAT  14                  // 2 paths x (3xW1 + 3xW2 + Wo)

typedef unsigned short bf16_t;
typedef __attribute__((ext_vector_type(8))) short short8;   // 8 bf16, 4 VGPRs
typedef __attribute__((ext_vector_type(4))) float f32x4;    // MFMA acc
typedef __attribute__((ext_vector_type(2))) float f32x2;

__device__ __forceinline__ float bf_lo(unsigned u) { return __uint_as_float(u << 16); }
__device__ __forceinline__ float bf_hi(unsigned u) { return __uint_as_float(u & 0xFFFF0000u); }
__device__ __forceinline__ bf16_t f2bf(float f) {   // RNE
    unsigned u = __float_as_uint(f);
    u += 0x7FFFu + ((u >> 16) & 1u);
    return (bf16_t)(u >> 16);
}
__device__ __forceinline__ unsigned pack2bf(float a, float b) {
    return (unsigned)f2bf(a) | ((unsigned)f2bf(b) << 16);
}

union S8U { short8 v; uint4 u4; unsigned us[4]; };

// ===========================================================================
// CSR build, fat-bin pipeline (no histogram pass):
//   init_bcur:   bcur[b] = b*BINCAP (fixed-stride fat bins in ACAT region)
//   bin_scatter: per-block LDS-staged binning, one contiguous reservation
//                per bin per block -> dense packed writes (dl<<16|src)
//   bin_scan:    counts from bcur -> compact start[197]; off[N] = NE
//   build_csr:   block per bin: stage fat bin in LDS, counting-sort by
//                local dst, emit per-node off[] + compact src bucket.
// ===========================================================================
__global__ __launch_bounds__(TPB) void init_bcur_kernel(int* __restrict__ bcur)
{
    int i = threadIdx.x;
    if (i < NBINS) bcur[i] = i * BINCAP;
}

__global__ __launch_bounds__(TPB) void bin_scatter_kernel(
    const int* __restrict__ src, const int* __restrict__ dst,
    int* __restrict__ bcur, unsigned* __restrict__ fatb)
{
    __shared__ int lcnt[NBINS];    // phase A: counts
    __shared__ int lcur[NBINS];    // phase C: absolute cursors
    const int tid = threadIdx.x;
    for (int i = tid; i < NBINS; i += TPB) lcnt[i] = 0;
    __syncthreads();

    unsigned pk[EPT];
    int bn[EPT];
    const int base = blockIdx.x * CHUNK;
    #pragma unroll
    for (int k = 0; k < EPT; ++k) {
        int e = base + k * TPB + tid;
        int b = -1; unsigned p = 0;
        if (e < NEDGES) {
            int d = dst[e];
            int s = src[e];
            b = d >> 8;
            p = ((unsigned)(d & 255) << 16) | (unsigned)s;
            atomicAdd(&lcnt[b], 1);
        }
        pk[k] = p; bn[k] = b;
    }
    __syncthreads();
    for (int i = tid; i < NBINS; i += TPB) {
        int c = lcnt[i];
        lcur[i] = (c > 0) ? atomicAdd(&bcur[i], c) : 0;
    }
    __syncthreads();
    #pragma unroll
    for (int k = 0; k < EPT; ++k) {
        if (bn[k] >= 0) {
            int p = atomicAdd(&lcur[bn[k]], 1);
            fatb[p] = pk[k];
        }
    }
}

__global__ __launch_bounds__(64) void bin_scan_kernel(
    const int* __restrict__ bcur, int* __restrict__ start, int* __restrict__ off)
{
    const int lane = threadIdx.x;   // 64 lanes, each owns 4 bins
    int c[4];
    int s = 0;
    #pragma unroll
    for (int k = 0; k < 4; ++k) {
        int b = 4 * lane + k;
        c[k] = (b < NBINS) ? (bcur[b] - b * BINCAP) : 0;
        s += c[k];
    }
    int incl = s;
    #pragma unroll
    for (int d = 1; d < 64; d <<= 1) {
        int t = __shfl_up(incl, d);
        if (lane >= d) incl += t;
    }
    int excl = incl - s;
    #pragma unroll
    for (int k = 0; k < 4; ++k) {
        int b = 4 * lane + k;
        if (b < NBINS) start[b] = excl;
        excl += c[k];
    }
    if (lane == 63) { start[NBINS] = excl; off[NNODES] = excl; }   // == NEDGES
}

__global__ __launch_bounds__(TPB) void build_csr_kernel(
    const int* __restrict__ start, const int* __restrict__ bcur,
    const unsigned* __restrict__ fatb, unsigned* __restrict__ bucket,
    int* __restrict__ off)
{
    __shared__ unsigned se[BINCAP];   // staged bin edges, 40 KB
    __shared__ int lcnt[BINSZ];
    __shared__ int lofs[BINSZ];
    __shared__ int wsum[4];
    const int tid = threadIdx.x;
    const int b = blockIdx.x;
    const int j0 = start[b];
    const int n = bcur[b] - b * BINCAP;   // <= BINCAP by construction
    const unsigned* fb = fatb + (size_t)b * BINCAP;

    lcnt[tid] = 0;
    for (int i = tid; i < n; i += TPB) se[i] = fb[i];
    __syncthreads();
    for (int i = tid; i < n; i += TPB) atomicAdd(&lcnt[se[i] >> 16], 1);
    __syncthreads();

    // exclusive scan of lcnt[256] across 4 waves
    const int lane = tid & 63, wid = tid >> 6;
    int v = lcnt[tid];
    int s = v;
    #pragma unroll
    for (int d = 1; d < 64; d <<= 1) {
        int t = __shfl_up(s, d);
        if (lane >= d) s += t;
    }
    if (lane == 63) wsum[wid] = s;
    __syncthreads();
    if (tid == 0) {
        int a = 0;
        #pragma unroll
        for (int k = 0; k < 4; ++k) { int t = wsum[k]; wsum[k] = a; a += t; }
    }
    __syncthreads();
    int excl = wsum[wid] + s - v;
    lofs[tid] = excl;
    int node = b * BINSZ + tid;
    if (node < NNODES) off[node] = j0 + excl;
    __syncthreads();

    // counting-sort scatter into compact bucket
    for (int i = tid; i < n; i += TPB) {
        unsigned e = se[i];
        int pos = atomicAdd(&lofs[e >> 16], 1);
        bucket[j0 + pos] = e & 0xFFFFu;   // src node id
    }
}

// ---------------------------------------------------------------------------
// One-time weight preconversion: all 14 matrices -> bf16 W^T in the exact
// padded [128][136] layout the LDS staging uses. Matrix b = p*7 + s,
// s: 0..2 = W1 layer, 3..5 = W2 layer, 6 = Wout.
// ---------------------------------------------------------------------------
__global__ __launch_bounds__(TPB) void convert_weights_kernel(
    const float* __restrict__ W1_0, const float* __restrict__ W2_0,
    const float* __restrict__ Wo_0,
    const float* __restrict__ W1_1, const float* __restrict__ W2_1,
    const float* __restrict__ Wo_1,
    bf16_t* __restrict__ wpre)
{
    const int b = blockIdx.x;
    const int p = b / 7, s = b % 7;
    const float* W;
    if (s < 3)      W = (p ? W1_1 : W1_0) + (size_t)s * DIM * DIM;
    else if (s < 6) W = (p ? W2_1 : W2_0) + (size_t)(s - 3) * DIM * DIM;
    else            W = p ? Wo_1 : Wo_0;
    bf16_t* dst = wpre + (size_t)b * WMAT;

    for (int idx = threadIdx.x; idx < 128 * 16; idx += TPB) {
        int n = idx & 127, koct = idx >> 7;
        float f[8];
        #pragma unroll
        for (int j = 0; j < 8; ++j) f[j] = W[(8 * koct + j) * 128 + n];
        uint4 u;
        u.x = pack2bf(f[0], f[1]); u.y = pack2bf(f[2], f[3]);
        u.z = pack2bf(f[4], f[5]); u.w = pack2bf(f[6], f[7]);
        *(uint4*)&dst[n * 136 + 8 * koct] = u;
    }
}

// ---------------------------------------------------------------------------
// Gather aggregation, wave per node, 16/8/1-deep ILP (round-9 proven;
// plateaued at ~3.9 TB/s L2-fill -- access-pattern throughput limit).
// ---------------------------------------------------------------------------
__global__ __launch_bounds__(TPB) void gather_agg_f32_kernel(
    const float* __restrict__ h, const int* __restrict__ off,
    const unsigned* __restrict__ bucket, float* __restrict__ acat)
{
    int node = blockIdx.x * (TPB / 64) + (threadIdx.x >> 6);
    int lane = threadIdx.x & 63;
    if (node >= NNODES) return;
    int j0 = off[node], j1 = off[node + 1];
    const float* base = h + 2 * lane;
    float ax = 0.0f, ay = 0.0f;
    int j = j0;
    for (; j + 16 <= j1; j += 16) {
        unsigned s[16];
        #pragma unroll
        for (int k = 0; k < 16; ++k) s[k] = bucket[j + k];
        float2 v[16];
        #pragma unroll
        for (int k = 0; k < 16; ++k) v[k] = *(const float2*)(base + (size_t)s[k] * DIM);
        #pragma unroll
        for (int k = 0; k < 16; ++k) { ax += v[k].x; ay += v[k].y; }
    }
    for (; j + 8 <= j1; j += 8) {
        unsigned s[8];
        #pragma unroll
        for (int k = 0; k < 8; ++k) s[k] = bucket[j + k];
        float2 v[8];
        #pragma unroll
        for (int k = 0; k < 8; ++k) v[k] = *(const float2*)(base + (size_t)s[k] * DIM);
        #pragma unroll
        for (int k = 0; k < 8; ++k) { ax += v[k].x; ay += v[k].y; }
    }
    for (; j < j1; ++j) {
        float2 v0 = *(const float2*)(base + (size_t)bucket[j] * DIM);
        ax += v0.x; ay += v0.y;
    }
    f32x2 r; r.x = ax; r.y = ay;
    __builtin_nontemporal_store(r, (f32x2*)(acat + (size_t)node * 256 + 2 * lane));
}

__global__ __launch_bounds__(TPB) void gather_cat_kernel(
    const bf16_t* __restrict__ hc, const int* __restrict__ off,
    const unsigned* __restrict__ bucket, float* __restrict__ acat)
{
    int node = blockIdx.x * (TPB / 64) + (threadIdx.x >> 6);
    int lane = threadIdx.x & 63;
    if (node >= NNODES) return;
    int j0 = off[node], j1 = off[node + 1];
    const uint2* base = (const uint2*)hc + lane;   // 64 uint2 per 512B row
    float a0 = 0.f, a1 = 0.f, a2 = 0.f, a3 = 0.f;
    int j = j0;
    for (; j + 16 <= j1; j += 16) {
        unsigned s[16];
        #pragma unroll
        for (int k = 0; k < 16; ++k) s[k] = bucket[j + k];
        uint2 u[16];
        #pragma unroll
        for (int k = 0; k < 16; ++k) u[k] = base[(size_t)s[k] * 64];
        #pragma unroll
        for (int k = 0; k < 16; ++k) {
            a0 += bf_lo(u[k].x); a1 += bf_hi(u[k].x);
            a2 += bf_lo(u[k].y); a3 += bf_hi(u[k].y);
        }
    }
    for (; j + 8 <= j1; j += 8) {
        unsigned s[8];
        #pragma unroll
        for (int k = 0; k < 8; ++k) s[k] = bucket[j + k];
        uint2 u[8];
        #pragma unroll
        for (int k = 0; k < 8; ++k) u[k] = base[(size_t)s[k] * 64];
        #pragma unroll
        for (int k = 0; k < 8; ++k) {
            a0 += bf_lo(u[k].x); a1 += bf_hi(u[k].x);
            a2 += bf_lo(u[k].y); a3 += bf_hi(u[k].y);
        }
    }
    for (; j < j1; ++j) {
        uint2 u = base[(size_t)bucket[j] * 64];
        a0 += bf_lo(u.x); a1 += bf_hi(u.x);
        a2 += bf_lo(u.y); a3 += bf_hi(u.y);
    }
    // lane<32: mean cols 4l..4l+3 -> acat[4l..]; lane>=32: std cols -> 128+...
    f32x4 r; r.x = a0; r.y = a1; r.z = a2; r.w = a3;
    __builtin_nontemporal_store(r, (f32x4*)(acat + (size_t)node * 256 + 4 * lane));
}

// ---------------------------------------------------------------------------
// FUSED GIN layer v4 (round-7 structure + issue-early A loads):
//   out_half = sigmoid(z@W1+b1)@W2+b2, z = (1+eps)*hin_half + agg_half.
//   ONE W LDS buffer (W1 then W2) + bf16 y1 = 52.2 KB -> 3 blocks/CU
//   (LDS-limited). __launch_bounds__(TPB,3): VGPR budget ~170, room for
//   the early-issued raw A loads (hin + acat) whose ~600-900cy latency
//   hides under W1 staging + barrier instead of serializing after it.
// ---------------------------------------------------------------------------
template <class HinT, int INSTRIDE>
__global__ __launch_bounds__(TPB, 3) void fused_layer_kernel(
    const HinT* __restrict__ hin, const float* __restrict__ acat, int aggByPath,
    const float* __restrict__ eps0, const float* __restrict__ eps1, int eps_idx,
    const float* __restrict__ W1_0, const float* __restrict__ b1_0,
    const float* __restrict__ W2_0, const float* __restrict__ b2_0,
    const float* __restrict__ W1_1, const float* __restrict__ b1_1,
    const float* __restrict__ W2_1, const float* __restrict__ b2_1,
    const bf16_t* __restrict__ wpre,
    bf16_t* __restrict__ out)
{
    __shared__ short sWt[128 * 136];   // 34.8 KB: W1^T, then W2^T
    __shared__ short y1b[64 * 136];    // 17.4 KB: bf16 y1

    const int p = (blockIdx.x >= NTILES) ? 1 : 0;
    const int t = blockIdx.x - p * NTILES;
    const int l = eps_idx;
    const float* W1 = p ? W1_1 : W1_0;
    const float* b1 = p ? b1_1 : b1_0;
    const float* W2 = p ? W2_1 : W2_0;
    const float* b2 = p ? b2_1 : b2_0;
    const float* epsp = p ? eps1 : eps0;
    const HinT* hbase = (INSTRIDE == 256) ? (hin + p * 128) : hin;
    const float* abase = acat + (aggByPath ? p * 128 : 0);
    bf16_t* ob = out + p * 128;

    const int tid = threadIdx.x;
    const int lane = tid & 63, w = tid >> 6;
    const int m = lane & 15, quad = lane >> 4;
    const int arow = min(t * 64 + 16 * w + m, NNODES - 1);

    // ---- ISSUE-EARLY: raw A-operand loads before W1 staging ----
    uint4  hraw16[4];
    float4 hraw32a[4], hraw32b[4];
    float4 araw0[4], araw1[4];
    #pragma unroll
    for (int k0 = 0; k0 < 4; ++k0) {
        const int kb = 32 * k0 + 8 * quad;
        if constexpr (sizeof(HinT) == 4) {
            const float* hp = (const float*)hbase + (size_t)arow * INSTRIDE + kb;
            hraw32a[k0] = *(const float4*)hp;
            hraw32b[k0] = *(const float4*)(hp + 4);
        } else {
            hraw16[k0] = *(const uint4*)((const bf16_t*)hbase + (size_t)arow * INSTRIDE + kb);
        }
        const float* ap = abase + (size_t)arow * 256 + kb;
        araw0[k0] = *(const float4*)ap;
        araw1[k0] = *(const float4*)(ap + 4);
    }

    // ---- stage W1^T (pure uint4 memcpy from wpre; fallback converts) ----
    if (wpre) {
        const uint4* s = (const uint4*)(wpre + (size_t)(p * 7 + l) * WMAT);
        uint4* d = (uint4*)sWt;
        #pragma unroll
        for (int i = 0; i < 9; ++i) {
            int idx = i * 256 + tid;
            if (idx < WMAT / 8) d[idx] = s[idx];
        }
    } else {
        #pragma unroll
        for (int it = 0; it < 8; ++it) {
            int idx = it * 256 + tid;
            int n = idx & 127, koct = idx >> 7;
            float f1[8];
            #pragma unroll
            for (int j = 0; j < 8; ++j) f1[j] = W1[(8 * koct + j) * 128 + n];
            uint4 u1;
            u1.x = pack2bf(f1[0], f1[1]); u1.y = pack2bf(f1[2], f1[3]);
            u1.z = pack2bf(f1[4], f1[5]); u1.w = pack2bf(f1[6], f1[7]);
            *(uint4*)&sWt[n * 136 + 8 * koct] = u1;
        }
    }
    __syncthreads();

    const float scale = 1.0f + epsp[eps_idx];
    float b1v[8], b2v[8];
    #pragma unroll
    for (int c = 0; c < 8; ++c) { b1v[c] = b1[16 * c + m]; b2v[c] = b2[16 * c + m]; }

    // ---- A-fragments from raw regs: z = scale*hin + agg, hi/lo split ----
    short8 afh[4], afl[4];
    #pragma unroll
    for (int k0 = 0; k0 < 4; ++k0) {
        float zf[8];
        if constexpr (sizeof(HinT) == 4) {
            zf[0] = hraw32a[k0].x; zf[1] = hraw32a[k0].y;
            zf[2] = hraw32a[k0].z; zf[3] = hraw32a[k0].w;
            zf[4] = hraw32b[k0].x; zf[5] = hraw32b[k0].y;
            zf[6] = hraw32b[k0].z; zf[7] = hraw32b[k0].w;
        } else {
            zf[0] = bf_lo(hraw16[k0].x); zf[1] = bf_hi(hraw16[k0].x);
            zf[2] = bf_lo(hraw16[k0].y); zf[3] = bf_hi(hraw16[k0].y);
            zf[4] = bf_lo(hraw16[k0].z); zf[5] = bf_hi(hraw16[k0].z);
            zf[6] = bf_lo(hraw16[k0].w); zf[7] = bf_hi(hraw16[k0].w);
        }
        zf[0] = fmaf(scale, zf[0], araw0[k0].x); zf[1] = fmaf(scale, zf[1], araw0[k0].y);
        zf[2] = fmaf(scale, zf[2], araw0[k0].z); zf[3] = fmaf(scale, zf[3], araw0[k0].w);
        zf[4] = fmaf(scale, zf[4], araw1[k0].x); zf[5] = fmaf(scale, zf[5], araw1[k0].y);
        zf[6] = fmaf(scale, zf[6], araw1[k0].z); zf[7] = fmaf(scale, zf[7], araw1[k0].w);
        S8U hi;
        hi.us[0] = pack2bf(zf[0], zf[1]); hi.us[1] = pack2bf(zf[2], zf[3]);
        hi.us[2] = pack2bf(zf[4], zf[5]); hi.us[3] = pack2bf(zf[6], zf[7]);
        afh[k0] = hi.v;
        S8U lo;
        float lw[8];
        lw[0] = zf[0] - bf_lo(hi.us[0]); lw[1] = zf[1] - bf_hi(hi.us[0]);
        lw[2] = zf[2] - bf_lo(hi.us[1]); lw[3] = zf[3] - bf_hi(hi.us[1]);
        lw[4] = zf[4] - bf_lo(hi.us[2]); lw[5] = zf[5] - bf_hi(hi.us[2]);
        lw[6] = zf[6] - bf_lo(hi.us[3]); lw[7] = zf[7] - bf_hi(hi.us[3]);
        lo.us[0] = pack2bf(lw[0], lw[1]); lo.us[1] = pack2bf(lw[2], lw[3]);
        lo.us[2] = pack2bf(lw[4], lw[5]); lo.us[3] = pack2bf(lw[6], lw[7]);
        afl[k0] = lo.v;
    }

    // ---- MFMA1: B-frags from LDS (read once per (k0,c), used twice) ----
    f32x4 acc[8];
    #pragma unroll
    for (int c = 0; c < 8; ++c) acc[c] = (f32x4){0.f, 0.f, 0.f, 0.f};
    #pragma unroll
    for (int k0 = 0; k0 < 4; ++k0) {
        const int kb = 32 * k0 + 8 * quad;
        #pragma unroll
        for (int c = 0; c < 8; ++c) {
            short8 bfr = *(const short8*)&sWt[(16 * c + m) * 136 + kb];
            acc[c] = __builtin_amdgcn_mfma_f32_16x16x32_bf16(afl[k0], bfr, acc[c], 0, 0, 0);
            acc[c] = __builtin_amdgcn_mfma_f32_16x16x32_bf16(afh[k0], bfr, acc[c], 0, 0, 0);
        }
    }

    // ---- sigmoid + stage y1 as bf16 ----
    const int rloc0 = 16 * w + 4 * quad;   // local row in [0,64)
    #pragma unroll
    for (int r = 0; r < 4; ++r) {
        #pragma unroll
        for (int c = 0; c < 8; ++c) {
            float y = acc[c][r] + b1v[c];
            y = 1.0f / (1.0f + expf(-y));
            y1b[(rloc0 + r) * 136 + 16 * c + m] = (short)f2bf(y);
        }
    }
    __syncthreads();   // MFMA1 sWt reads + y1 writes complete

    // ---- stage W2^T into the same buffer ----
    if (wpre) {
        const uint4* s = (const uint4*)(wpre + (size_t)(p * 7 + 3 + l) * WMAT);
        uint4* d = (uint4*)sWt;
        #pragma unroll
        for (int i = 0; i < 9; ++i) {
            int idx = i * 256 + tid;
            if (idx < WMAT / 8) d[idx] = s[idx];
        }
    } else {
        #pragma unroll
        for (int it = 0; it < 8; ++it) {
            int idx = it * 256 + tid;
            int n = idx & 127, koct = idx >> 7;
            float f2[8];
            #pragma unroll
            for (int j = 0; j < 8; ++j) f2[j] = W2[(8 * koct + j) * 128 + n];
            uint4 u2;
            u2.x = pack2bf(f2[0], f2[1]); u2.y = pack2bf(f2[2], f2[3]);
            u2.z = pack2bf(f2[4], f2[5]); u2.w = pack2bf(f2[6], f2[7]);
            *(uint4*)&sWt[n * 136 + 8 * koct] = u2;
        }
    }
    __syncthreads();

    // ---- MFMA2: A from y1b (bf16 direct), B from sWt ----
    f32x4 acc2[8];
    #pragma unroll
    for (int c = 0; c < 8; ++c) acc2[c] = (f32x4){0.f, 0.f, 0.f, 0.f};
    #pragma unroll
    for (int k0 = 0; k0 < 4; ++k0) {
        const int kb = 32 * k0 + 8 * quad;
        short8 a2 = *(const short8*)&y1b[(16 * w + m) * 136 + kb];
        #pragma unroll
        for (int c = 0; c < 8; ++c) {
            short8 b2f = *(const short8*)&sWt[(16 * c + m) * 136 + kb];
            acc2[c] = __builtin_amdgcn_mfma_f32_16x16x32_bf16(a2, b2f, acc2[c], 0, 0, 0);
        }
    }

    // ---- epilogue: h_out = acc2 + b2 (bf16, stride 256) ----
    const int row0 = t * 64 + 16 * w + 4 * quad;
    #pragma unroll
    for (int r = 0; r < 4; ++r) {
        const int grow = row0 + r;
        if (grow < NNODES) {
            bf16_t* op = ob + (size_t)grow * 256 + m;
            #pragma unroll
            for (int c = 0; c < 8; ++c) op[16 * c] = f2bf(acc2[c][r] + b2v[c]);
        }
    }
}

// ---------------------------------------------------------------------------
// Final projection + layernorm, both paths in one grid:
//   out(p) = layernorm(h_cat(p) @ Wout + bout) * gamma + beta  (fp32)
// ---------------------------------------------------------------------------
__global__ __launch_bounds__(TPB) void final_proj_kernel(
    const bf16_t* __restrict__ hc,
    const float* __restrict__ Wo0, const float* __restrict__ bo0,
    const float* __restrict__ Wo1, const float* __restrict__ bo1,
    const float* __restrict__ gamma, const float* __restrict__ beta,
    const bf16_t* __restrict__ wpre,
    float* __restrict__ M, float* __restrict__ V)
{
    __shared__ short sWt[128 * 136];   // bf16 W^T

    const int p = (blockIdx.x >= NTILES) ? 1 : 0;
    const int t = blockIdx.x - p * NTILES;
    const float* W = p ? Wo1 : Wo0;
    const float* bias = p ? bo1 : bo0;
    const bf16_t* hbase = hc + p * 128;
    float* out = p ? V : M;

    const int tid = threadIdx.x;
    const int lane = tid & 63, w = tid >> 6;
    const int m = lane & 15, quad = lane >> 4;
    const int arow = min(t * 64 + 16 * w + m, NNODES - 1);

    // issue-early A loads
    short8 af[4];
    #pragma unroll
    for (int k0 = 0; k0 < 4; ++k0)
        af[k0] = *(const short8*)(hbase + (size_t)arow * 256 + 32 * k0 + 8 * quad);

    if (wpre) {
        const uint4* s = (const uint4*)(wpre + (size_t)(p * 7 + 6) * WMAT);
        uint4* d = (uint4*)sWt;
        #pragma unroll
        for (int i = 0; i < 9; ++i) {
            int idx = i * 256 + tid;
            if (idx < WMAT / 8) d[idx] = s[idx];
        }
    } else {
        #pragma unroll
        for (int it = 0; it < 8; ++it) {
            int idx = it * 256 + tid;
            int n = idx & 127, koct = idx >> 7;
            float f[8];
            #pragma unroll
            for (int j = 0; j < 8; ++j) f[j] = W[(8 * koct + j) * 128 + n];
            uint4 u;
            u.x = pack2bf(f[0], f[1]); u.y = pack2bf(f[2], f[3]);
            u.z = pack2bf(f[4], f[5]); u.w = pack2bf(f[6], f[7]);
            *(uint4*)&sWt[n * 136 + 8 * koct] = u;
        }
    }
    __syncthreads();

    float bias_v[8], g_v[8], bt_v[8];
    #pragma unroll
    for (int c = 0; c < 8; ++c) {
        bias_v[c] = bias[16 * c + m];
        g_v[c] = gamma[16 * c + m];
        bt_v[c] = beta[16 * c + m];
    }

    f32x4 acc[8];
    #pragma unroll
    for (int c = 0; c < 8; ++c) acc[c] = (f32x4){0.f, 0.f, 0.f, 0.f};
    #pragma unroll
    for (int k0 = 0; k0 < 4; ++k0) {
        const int kb = 32 * k0 + 8 * quad;
        #pragma unroll
        for (int c = 0; c < 8; ++c)
            acc[c] = __builtin_amdgcn_mfma_f32_16x16x32_bf16(
                af[k0], *(const short8*)&sWt[(16 * c + m) * 136 + kb], acc[c], 0, 0, 0);
    }

    const int row0 = t * 64 + 16 * w + 4 * quad;
    #pragma unroll
    for (int r = 0; r < 4; ++r) {
        const int grow = row0 + r;
        float y[8];
        #pragma unroll
        for (int c = 0; c < 8; ++c) y[c] = acc[c][r] + bias_v[c];
        float s1 = 0.f, s2 = 0.f;
        #pragma unroll
        for (int c = 0; c < 8; ++c) { s1 += y[c]; s2 = fmaf(y[c], y[c], s2); }
        #pragma unroll
        for (int d = 1; d < 16; d <<= 1) {
            s1 += __shfl_xor(s1, d);
            s2 += __shfl_xor(s2, d);
        }
        float mean = s1 * (1.0f / DIM);
        float var  = s2 * (1.0f / DIM) - mean * mean;
        float rstd = rsqrtf(var + 1e-5f);
        if (grow < NNODES) {
            float* op = out + (size_t)grow * DIM + m;
            #pragma unroll
            for (int c = 0; c < 8; ++c)
                op[16 * c] = fmaf((y[c] - mean) * rstd, g_v[c], bt_v[c]);
        }
    }
}

// ---------------------------------------------------------------------------
// samples = mean + eps*std; eps = jax.random.normal(key(42)), partitionable
// threefry: block inputs (0, i), bits = out0 ^ out1, key (0,42).
// ---------------------------------------------------------------------------
__device__ __forceinline__ unsigned rotl32(unsigned x, int r) {
    return (x << r) | (x >> (32 - r));
}

__device__ __forceinline__ unsigned threefry_xor(unsigned c0, unsigned c1) {
    const unsigned k0 = 0u, k1 = 42u;
    const unsigned k2 = k0 ^ k1 ^ 0x1BD11BDAu;
    unsigned x0 = c0 + k0;
    unsigned x1 = c1 + k1;
#define TF_ROUND(R) { x0 += x1; x1 = rotl32(x1, R); x1 ^= x0; }
    TF_ROUND(13) TF_ROUND(15) TF_ROUND(26) TF_ROUND(6)
    x0 += k1; x1 += k2 + 1u;
    TF_ROUND(17) TF_ROUND(29) TF_ROUND(16) TF_ROUND(24)
    x0 += k2; x1 += k0 + 2u;
    TF_ROUND(13) TF_ROUND(15) TF_ROUND(26) TF_ROUND(6)
    x0 += k0; x1 += k1 + 3u;
    TF_ROUND(17) TF_ROUND(29) TF_ROUND(16) TF_ROUND(24)
    x0 += k1; x1 += k2 + 4u;
    TF_ROUND(13) TF_ROUND(15) TF_ROUND(26) TF_ROUND(6)
    x0 += k2; x1 += k0 + 5u;
#undef TF_ROUND
    return x0 ^ x1;
}

__device__ __forceinline__ float bits_to_normal(unsigned bits) {
    float f = __uint_as_float((bits >> 9) | 0x3F800000u) - 1.0f;
    const float lo = -0.99999994f;
    float u = __fadd_rn(__fmul_rn(f, 2.0f), lo);
    u = fmaxf(lo, u);
    float w = -log1pf(-(u * u));
    float p;
    if (w < 5.0f) {
        w -= 2.5f;
        p = 2.81022636e-08f;
        p = fmaf(p, w, 3.43273939e-07f);
        p = fmaf(p, w, -3.5233877e-06f);
        p = fmaf(p, w, -4.39150654e-06f);
        p = fmaf(p, w, 0.00021858087f);
        p = fmaf(p, w, -0.00125372503f);
        p = fmaf(p, w, -0.00417768164f);
        p = fmaf(p, w, 0.246640727f);
        p = fmaf(p, w, 1.50140941f);
    } else {
        w = sqrtf(w) - 3.0f;
        p = -0.000200214257f;
        p = fmaf(p, w, 0.000100950558f);
        p = fmaf(p, w, 0.00134934322f);
        p = fmaf(p, w, -0.00367342844f);
        p = fmaf(p, w, 0.00573950773f);
        p = fmaf(p, w, -0.0076224613f);
        p = fmaf(p, w, 0.00943887047f);
        p = fmaf(p, w, 1.00167406f);
        p = fmaf(p, w, 2.83297682f);
    }
    return 1.41421356f * (p * u);
}

__global__ __launch_bounds__(TPB) void samples_kernel(
    const float* __restrict__ mean_v, const float* __restrict__ std_v,
    float* __restrict__ samples)
{
    int t = blockIdx.x * TPB + threadIdx.x;
    if (t >= NHID / 4) return;
    float4 m = ((const float4*)mean_v)[t];
    float4 s = ((const float4*)std_v)[t];
    float e[4];
    #pragma unroll
    for (int q = 0; q < 4; q++) {
        unsigned i = 4u * (unsigned)t + (unsigned)q;
        e[q] = bits_to_normal(threefry_xor(0u, i));
    }
    f32x4 r;
    r.x = fmaf(e[0], s.x, m.x);
    r.y = fmaf(e[1], s.y, m.y);
    r.z = fmaf(e[2], s.z, m.z);
    r.w = fmaf(e[3], s.w, m.w);
    __builtin_nontemporal_store(r, (f32x4*)samples + t);
}

// ---------------------------------------------------------------------------
// Orchestration (layer-interleaved paths, concatenated h, preconv weights,
// fat-bin CSR build -- no histogram pass):
//   convert -> init_bcur -> bin_scatter(fat in ACAT) -> bin_scan ->
//   build_csr -> L0 f32 gather -> fused0 -> [gather_cat -> fused_l] x2 ->
//   final_proj -> samples.  12 dispatches, no memset.
//   Buffers: h_cat = S (25.6MB bf16); acat = M..V (51.2MB f32); fat bucket
//   (8MB) staged in ACAT (dead until first gather); samples -> S.
//   d_ws: start[197]|bcur[196]|off[50001]|bucket[NE]|wpre[14 mats].
// ---------------------------------------------------------------------------
extern "C" void kernel_launch(void* const* d_in, const int* in_sizes, int n_in,
                              void* d_out, int out_size, void* d_ws, size_t ws_size,
                              hipStream_t stream)
{
    const float* x     = (const float*)d_in[0];
    const int*   esrc  = (const int*)d_in[1];
    const int*   edst  = (const int*)d_in[2];
    const float* prm[2][7];
    for (int p = 0; p < 2; p++)
        for (int i = 0; i < 7; i++)
            prm[p][i] = (const float*)d_in[3 + p * 7 + i];
    const float* gamma = (const float*)d_in[17];
    const float* beta  = (const float*)d_in[18];

    float*  S  = (float*)d_out;
    float*  M  = S + NHID;
    float*  V  = M + NHID;
    bf16_t* Hc = (bf16_t*)S;     // h_cat [50000][256] bf16 = 25.6 MB
    float*  ACAT = M;            // [50000][256] f32 spans M..V = 51.2 MB
    unsigned* fatb = (unsigned*)M;   // fat bins, 196*10240*4B = 8MB (pre-gather)

    int* start = (int*)d_ws;                       // NBINS + 1
    int* bcur  = start + NBINS + 1;                // NBINS
    int* off   = bcur + NBINS;                     // NNODES + 1
    unsigned* bucket = (unsigned*)(off + NNODES + 1);  // NEDGES

    size_t csr_bytes = ((char*)(bucket + NEDGES)) - (char*)d_ws;
    size_t wpre_off  = (csr_bytes + 15) & ~(size_t)15;
    size_t need      = wpre_off + (size_t)NWMAT * WMAT * sizeof(bf16_t);
    bf16_t* wpre = (ws_size >= need) ? (bf16_t*)((char*)d_ws + wpre_off) : nullptr;

    const dim3 gChunk(NCHUNKS);
    const dim3 gBin(NBINS);
    const dim3 gGather((NNODES + (TPB / 64) - 1) / (TPB / 64));
    const dim3 gTile2(2 * NTILES);
    const dim3 gSamp((NHID / 4 + TPB - 1) / TPB);

    if (wpre)
        convert_weights_kernel<<<dim3(NWMAT), TPB, 0, stream>>>(
            prm[0][0], prm[0][2], prm[0][5], prm[1][0], prm[1][2], prm[1][5], wpre);
    init_bcur_kernel<<<1, TPB, 0, stream>>>(bcur);
    bin_scatter_kernel<<<gChunk, TPB, 0, stream>>>(esrc, edst, bcur, fatb);
    bin_scan_kernel<<<1, 64, 0, stream>>>(bcur, start, off);
    build_csr_kernel<<<gBin, TPB, 0, stream>>>(start, bcur, fatb, bucket, off);

    // shared layer-0 aggregation (fp32 x) -> acat mean-half
    gather_agg_f32_kernel<<<gGather, TPB, 0, stream>>>(x, off, bucket, ACAT);

    // layer 0, both paths: z = (1+eps)*x + agg0 -> h_cat halves
    fused_layer_kernel<float, DIM><<<gTile2, TPB, 0, stream>>>(
        x, ACAT, 0, prm[0][4], prm[1][4], 0,
        prm[0][0], prm[0][1], prm[0][2], prm[0][3],
        prm[1][0], prm[1][1], prm[1][2], prm[1][3], wpre, Hc);

    for (int l = 1; l < 3; l++) {
        gather_cat_kernel<<<gGather, TPB, 0, stream>>>(Hc, off, bucket, ACAT);
        fused_layer_kernel<bf16_t, 256><<<gTile2, TPB, 0, stream>>>(
            Hc, ACAT, 1, prm[0][4], prm[1][4], l,
            prm[0][0] + (size_t)l * DIM * DIM, prm[0][1] + l * DIM,
            prm[0][2] + (size_t)l * DIM * DIM, prm[0][3] + l * DIM,
            prm[1][0] + (size_t)l * DIM * DIM, prm[1][1] + l * DIM,
            prm[1][2] + (size_t)l * DIM * DIM, prm[1][3] + l * DIM, wpre, Hc);
    }

    final_proj_kernel<<<gTile2, TPB, 0, stream>>>(
        Hc, prm[0][5], prm[0][6], prm[1][5], prm[1][6], gamma, beta, wpre, M, V);

    samples_kernel<<<gSamp, TPB, 0, stream>>>(M, V, S);
}